// Round 15
// baseline (812.136 us; speedup 1.0000x reference)
//
#include <hip/hip_runtime.h>
#include <math.h>

typedef __attribute__((ext_vector_type(8))) __bf16 bf16x8;
typedef __attribute__((ext_vector_type(4))) float f32x4;
typedef __attribute__((ext_vector_type(8))) unsigned short u16x8;

#define DI __device__ __forceinline__

DI float b2f(unsigned short u) { return __uint_as_float(((unsigned int)u) << 16); }
DI unsigned short f2b(float f) {
    unsigned int x = __float_as_uint(f);
    x += 0x7fffu + ((x >> 16) & 1u);   // round-to-nearest-even
    return (unsigned short)(x >> 16);
}
DI unsigned short f2b_fast(float f) {
    __bf16 h = (__bf16)f;
    return *(unsigned short*)&h;
}

// async global -> LDS, 16 B per lane (dest = wave-uniform base + lane*16)
DI void gl16(const unsigned short* g, unsigned short* l) {
    __builtin_amdgcn_global_load_lds(
        (const __attribute__((address_space(1))) void*)g,
        (__attribute__((address_space(3))) void*)l,
        16, 0, 0);
}

// tanh-GELU, algebraic: 0.5v(1+tanh(u)) == v * sigmoid(2u)
DI float gelu_f(float v) {
    float y = -1.5957691216f * v - 0.0713548163f * v * v * v;   // -2u
    return v * __builtin_amdgcn_rcpf(1.f + __expf(y));
}

// B=16, H=W=56, L=3136, C=384, NH=12, HD=32, WS=8, nW=49, N=64, NQ=64, MLP_H=1536
#define SCALE_ATT 0.17677669529663687f
#define BN_SCALE  0.9999950000374997f   // 1/sqrt(1+1e-5)

// ---------------- merged fp32 [K][N] -> bf16 [N][K] for all 4 weights ----------------
__global__ __launch_bounds__(256) void cvt_all(const float* __restrict__ s0, const float* __restrict__ s1,
                                               const float* __restrict__ s2, const float* __restrict__ s3,
                                               unsigned short* __restrict__ d0, unsigned short* __restrict__ d1,
                                               unsigned short* __restrict__ d2, unsigned short* __restrict__ d3) {
    int b = blockIdx.x;
    const float* in;
    unsigned short* out;
    int Kd, Nd, i0;
    if (b < 1728)      { in = s0; out = d0; Kd = 384;  Nd = 1152; i0 = b * 256; }
    else if (b < 2304) { in = s1; out = d1; Kd = 384;  Nd = 384;  i0 = (b - 1728) * 256; }
    else if (b < 4608) { in = s2; out = d2; Kd = 384;  Nd = 1536; i0 = (b - 2304) * 256; }
    else               { in = s3; out = d3; Kd = 1536; Nd = 384;  i0 = (b - 4608) * 256; }
    int i = i0 + threadIdx.x;
    if (i < Kd * Nd) {
        int k = i / Nd, n = i % Nd;
        out[(size_t)n * Kd + k] = f2b(in[i]);
    }
}

// ---------------- LayerNorm (row = 384), fp32 in -> bf16 out, vectorized ----------------
__global__ __launch_bounds__(64) void ln_kernel(const float* __restrict__ xin,
                                                const float* __restrict__ g,
                                                const float* __restrict__ bsh,
                                                unsigned short* __restrict__ out) {
    int row = blockIdx.x;
    int t = threadIdx.x;
    size_t base = (size_t)row * 384;
    float2 v[3];
    float s = 0.f, q = 0.f;
#pragma unroll
    for (int p = 0; p < 3; ++p) {
        v[p] = *(const float2*)(xin + base + p * 128 + t * 2);
        s += v[p].x + v[p].y;
        q += v[p].x * v[p].x + v[p].y * v[p].y;
    }
#pragma unroll
    for (int off = 32; off > 0; off >>= 1) {
        s += __shfl_xor(s, off);
        q += __shfl_xor(q, off);
    }
    float mu = s * (1.f / 384.f);
    float rstd = rsqrtf(q * (1.f / 384.f) - mu * mu + 1e-5f);
#pragma unroll
    for (int p = 0; p < 3; ++p) {
        int c = p * 128 + t * 2;
        unsigned int lo16 = f2b((v[p].x - mu) * rstd * g[c] + bsh[c]);
        unsigned int hi16 = f2b((v[p].y - mu) * rstd * g[c + 1] + bsh[c + 1]);
        ((unsigned int*)(out + base + p * 128))[t] = lo16 | (hi16 << 16);
    }
}

// ---------------- 8x8 average pool ----------------
__global__ __launch_bounds__(384) void pool_kernel(const unsigned short* __restrict__ xn,
                                                   float* __restrict__ pooled) {
    int blk = blockIdx.x;
    int b = blk / 49, pp = blk % 49;
    int ph = pp / 7, pw = pp % 7;
    int c = threadIdx.x;
    float s = 0.f;
    for (int i = 0; i < 8; ++i) {
        size_t rb = ((size_t)b * 3136 + (size_t)(ph * 8 + i) * 56 + pw * 8) * 384;
        for (int j = 0; j < 8; ++j) s += b2f(xn[rb + (size_t)j * 384 + c]);
    }
    pooled[(size_t)blk * 384 + c] = s * (1.f / 64.f);
}

// ---------------- key/value conv1x1 + BN ----------------
__global__ __launch_bounds__(128) void kvproj_kernel(
    const float* __restrict__ pooled,
    const float* __restrict__ kw, const float* __restrict__ kb,
    const float* __restrict__ kg, const float* __restrict__ kbb,
    const float* __restrict__ vw, const float* __restrict__ vb,
    const float* __restrict__ vg, const float* __restrict__ vbb,
    float* __restrict__ keyo, float* __restrict__ valo) {
    __shared__ float row[384];
    int r = blockIdx.x;
    int t = threadIdx.x;
    for (int c = t; c < 384; c += 128) row[c] = pooled[(size_t)r * 384 + c];
    __syncthreads();
#pragma unroll
    for (int p = 0; p < 3; ++p) {
        int c = t + 128 * p;
        float aK = 0.f, aV = 0.f;
        for (int k = 0; k < 384; ++k) {
            float rv = row[k];
            aK += rv * kw[(size_t)k * 384 + c];
            aV += rv * vw[(size_t)k * 384 + c];
        }
        keyo[(size_t)r * 384 + c] = (aK + kb[c]) * BN_SCALE * kg[c] + kbb[c];
        valo[(size_t)r * 384 + c] = (aV + vb[c]) * BN_SCALE * vg[c] + vbb[c];
    }
}

// ---------------- rel-pos bias expand ----------------
__global__ __launch_bounds__(64) void rpb_expand_kernel(const float* __restrict__ rpbt,
                                                        float* __restrict__ rpb_mat) {
    int h = blockIdx.x >> 6, q = blockIdx.x & 63;
    int k = threadIdx.x;
    int i1 = q >> 3, j1 = q & 7, i2 = k >> 3, j2 = k & 7;
    rpb_mat[((size_t)h * 64 + q) * 64 + k] = rpbt[(size_t)((i1 - i2 + 7) * 15 + (j1 - j2 + 7)) * 12 + h];
}

// ---------------- global cross attention ----------------
__global__ __launch_bounds__(64) void cross_attn_kernel(const float* __restrict__ keyg,
                                                        const float* __restrict__ valg,
                                                        const float* __restrict__ qtok,
                                                        float* __restrict__ o) {
    int b = blockIdx.x / 12, h = blockIdx.x % 12;
    __shared__ float kk[49][32];
    __shared__ float vv[49][32];
    int t = threadIdx.x;
    for (int idx = t; idx < 49 * 32; idx += 64) {
        int k = idx >> 5, d = idx & 31;
        size_t gidx = ((size_t)b * 49 + k) * 384 + h * 32 + d;
        kk[k][d] = keyg[gidx];
        vv[k][d] = valg[gidx];
    }
    __syncthreads();
    float q[32];
#pragma unroll
    for (int d = 0; d < 32; ++d) q[d] = qtok[(size_t)t * 384 + h * 32 + d] * SCALE_ATT;
    float lg[49];
    float mx = -1e30f;
#pragma unroll
    for (int k = 0; k < 49; ++k) {
        float s = 0.f;
#pragma unroll
        for (int d = 0; d < 32; ++d) s += q[d] * kk[k][d];
        lg[k] = s;
        mx = fmaxf(mx, s);
    }
    float sum = 0.f;
#pragma unroll
    for (int k = 0; k < 49; ++k) { float e = expf(lg[k] - mx); lg[k] = e; sum += e; }
    float inv = 1.f / sum;
    float od[32];
#pragma unroll
    for (int d = 0; d < 32; ++d) od[d] = 0.f;
#pragma unroll
    for (int k = 0; k < 49; ++k) {
        float wgt = lg[k];
#pragma unroll
        for (int d = 0; d < 32; ++d) od[d] += wgt * vv[k][d];
    }
#pragma unroll
    for (int d = 0; d < 32; ++d) o[((size_t)b * 64 + t) * 384 + h * 32 + d] = od[d] * inv;
}

// ---------------- gk/gv ----------------
__global__ __launch_bounds__(128) void gkv_kernel(
    const float* __restrict__ o, const float* __restrict__ qtok,
    const float* __restrict__ ckw, const float* __restrict__ ckb,
    const float* __restrict__ cvw, const float* __restrict__ cvb,
    unsigned short* __restrict__ gk, unsigned short* __restrict__ gv) {
    __shared__ float row[384];
    int r = blockIdx.x;
    int n = r & 63;
    int t = threadIdx.x;
    for (int c = t; c < 384; c += 128)
        row[c] = o[(size_t)r * 384 + c] + qtok[(size_t)n * 384 + c];
    __syncthreads();
#pragma unroll
    for (int p = 0; p < 3; ++p) {
        int c = t + 128 * p;
        float aK = 0.f, aV = 0.f;
        for (int k = 0; k < 384; ++k) {
            float rv = row[k];
            aK += rv * ckw[(size_t)k * 384 + c];
            aV += rv * cvw[(size_t)k * 384 + c];
        }
        gk[(size_t)r * 384 + c] = f2b(aK + ckb[c]);
        gv[(size_t)r * 384 + c] = f2b(aV + cvb[c]);
    }
}

// ---------------- MFMA GEMM, 128x128 tile, 4 waves ----------------
// A: 3-buffer LDS via global_load_lds (T2-swizzled, counted vmcnt).
// B: 3-slot REGISTER prefetch direct from L2-resident W^T (no LDS, no barrier coupling).
// 6 vmem ops/tile (2 gl16 A + 4 B-frag loads); 2 tiles in flight -> steady wait vmcnt(6).
// LDS = 24 KB. Static slot indices everywhere (rule #20).
template <int MODE>
__global__ __launch_bounds__(256, 3) void gemm128(const unsigned short* __restrict__ A,
                                                  const unsigned short* __restrict__ BT,
                                                  const float* __restrict__ bias,
                                                  int N, int K,
                                                  void* __restrict__ outp,
                                                  const void* __restrict__ aux0) {
    __shared__ __align__(16) unsigned short As[3][128 * 32];

    // XCD-aware bijective swizzle
    int nwg = gridDim.x * gridDim.y;
    int flat = blockIdx.y * gridDim.x + blockIdx.x;
    int flat2 = (flat & 7) * (nwg >> 3) + (flat >> 3);
    int bn = flat2 % gridDim.x, bm = flat2 / gridDim.x;

    int t = threadIdx.x;
    int w = t >> 6, lane = t & 63;
    int wm = w >> 1, wn = w & 1;
    int lo = lane & 15, g = lane >> 4;

    f32x4 acc[4][4];
#pragma unroll
    for (int i = 0; i < 4; ++i)
#pragma unroll
        for (int j = 0; j < 4; ++j) acc[i][j] = f32x4{0.f, 0.f, 0.f, 0.f};

    int srow = w * 32 + (lane >> 2);
    int schunk = (((lane & 3) ^ ((srow >> 1) & 3)) << 3);   // swizzled global k-chunk (A only)
    const unsigned short* Ap0 = A + (size_t)(bm * 128 + srow) * K + schunk;
    const unsigned short* Ap1 = A + (size_t)(bm * 128 + srow + 16) * K + schunk;
    int d0 = (w * 32) * 32, d1 = (w * 32 + 16) * 32;
    int gx = ((g ^ ((lo >> 1) & 3)) << 3);

    // B register prefetch base: frag n = row (bn*128 + wn*64 + n*16 + lo), bytes [g*16..)
    const unsigned short* Bbase = BT + (size_t)(bn * 128 + wn * 64 + lo) * K + g * 8;
    size_t nK16 = (size_t)16 * K;
    bf16x8 Breg[3][4];

#define STAGE(buf, kb)                    \
    do {                                  \
        gl16(Ap0 + (kb), As[buf] + d0);   \
        gl16(Ap1 + (kb), As[buf] + d1);   \
    } while (0)

#define LOADB(slot, kb)                                                        \
    do {                                                                       \
        _Pragma("unroll")                                                      \
        for (int n = 0; n < 4; ++n)                                            \
            Breg[slot][n] = *(const bf16x8*)(Bbase + (size_t)n * nK16 + (kb)); \
    } while (0)

#define WAIT6() asm volatile("s_waitcnt vmcnt(6)" ::: "memory")
#define WAIT0() asm volatile("s_waitcnt vmcnt(0)" ::: "memory")

#define COMPUTE(slot)                                                                    \
    do {                                                                                 \
        bf16x8 af[4];                                                                    \
        _Pragma("unroll")                                                                \
        for (int m = 0; m < 4; ++m)                                                      \
            af[m] = *(const bf16x8*)(As[slot] + (wm * 64 + m * 16 + lo) * 32 + gx);      \
        __builtin_amdgcn_s_setprio(1);                                                   \
        _Pragma("unroll")                                                                \
        for (int m = 0; m < 4; ++m)                                                      \
            _Pragma("unroll")                                                            \
            for (int n = 0; n < 4; ++n)                                                  \
                acc[m][n] = __builtin_amdgcn_mfma_f32_16x16x32_bf16(af[m], Breg[slot][n],\
                                                                    acc[m][n], 0, 0, 0); \
        __builtin_amdgcn_s_setprio(0);                                                   \
    } while (0)

    // prologue: 2 tiles in flight (12 outstanding vm ops per wave)
    STAGE(0, 0);
    LOADB(0, 0);
    STAGE(1, 32);
    LOADB(1, 32);

    int nt = K >> 5;   // 12 or 48 -> divisible by 3
    for (int tt = 0; tt < nt; tt += 3) {
        if (tt + 1 < nt) WAIT6(); else WAIT0();
        __builtin_amdgcn_s_barrier();
        if (tt + 2 < nt) { STAGE(2, (tt + 2) * 32); LOADB(2, (tt + 2) * 32); }
        COMPUTE(0);
        if (tt + 2 < nt) WAIT6(); else WAIT0();
        __builtin_amdgcn_s_barrier();
        if (tt + 3 < nt) { STAGE(0, (tt + 3) * 32); LOADB(0, (tt + 3) * 32); }
        COMPUTE(1);
        if (tt + 3 < nt) WAIT6(); else WAIT0();
        __builtin_amdgcn_s_barrier();
        if (tt + 4 < nt) { STAGE(1, (tt + 4) * 32); LOADB(1, (tt + 4) * 32); }
        COMPUTE(2);
    }
#undef STAGE
#undef LOADB
#undef WAIT6
#undef WAIT0
#undef COMPUTE

    int r0 = bm * 128 + wm * 64 + g * 4;
    int c0 = bn * 128 + wn * 64 + lo;
    // MODE 1 hoist: r>>6 == bm*2+wm (thread-constant since m*16+g*4+j < 64)
    int wgc = bm * 2 + wm;
    int bC = wgc / 49, winC = wgc % 49;
    int whC = winC / 7, wwC = winC % 7;
    int lC = (whC << 3) * 56 + (wwC << 3);
    size_t rowbaseC = (size_t)bC * 3136;
#pragma unroll
    for (int m = 0; m < 4; ++m)
#pragma unroll
        for (int n = 0; n < 4; ++n)
#pragma unroll
            for (int j = 0; j < 4; ++j) {
                int r = r0 + m * 16 + j;
                int c = c0 + n * 16;
                float v = acc[m][n][j] + bias[c];
                if (MODE == 0) {
                    ((unsigned short*)outp)[(size_t)r * N + c] = f2b(v);
                } else if (MODE == 1) {
                    int nn = m * 16 + (g << 2) + j;          // r & 63
                    int l = lC + (nn >> 3) * 56 + (nn & 7);
                    size_t idx = (rowbaseC + l) * 384 + c;
                    ((float*)outp)[idx] = ((const float*)aux0)[idx] + v;
                } else if (MODE == 2) {
                    ((unsigned short*)outp)[(size_t)r * N + c] = f2b(gelu_f(v));
                } else {
                    float res = ((const float*)aux0)[(size_t)r * 384 + c];
                    ((float*)outp)[(size_t)r * N + c] = v + res;
                }
            }
}

// ---------------- MFMA windowed attention: one wave per (window, head) ----------------
__global__ __launch_bounds__(64, 2) void win_attn_mfma(const unsigned short* __restrict__ qkv,
                                                       const unsigned short* __restrict__ gkb,
                                                       const unsigned short* __restrict__ gvb,
                                                       const float* __restrict__ rpb_mat,
                                                       unsigned short* __restrict__ ow) {
    int blk = blockIdx.x;
    int wg = blk / 12, h = blk % 12;
    int b = wg / 49, win = wg % 49;
    int wh = win / 7, ww = win % 7;
    int lane = threadIdx.x;
    int lo = lane & 15, g = lane >> 4;

    __shared__ __align__(16) unsigned short VT[32 * 136];
    __shared__ __align__(16) unsigned short PL[64 * 40];

    size_t qkvbase = (size_t)b * 3136 * 1152;
    int lbase = ((wh << 3)) * 56 + (ww << 3);

    {
        int n = lane;
        int l = lbase + (n >> 3) * 56 + (n & 7);
        const unsigned short* vp = qkv + qkvbase + (size_t)l * 1152 + 768 + h * 32;
        u16x8 v0 = *(const u16x8*)(vp);
        u16x8 v1 = *(const u16x8*)(vp + 8);
        u16x8 v2 = *(const u16x8*)(vp + 16);
        u16x8 v3 = *(const u16x8*)(vp + 24);
#pragma unroll
        for (int j = 0; j < 8; ++j) {
            VT[(0 + j) * 136 + n]  = v0[j];
            VT[(8 + j) * 136 + n]  = v1[j];
            VT[(16 + j) * 136 + n] = v2[j];
            VT[(24 + j) * 136 + n] = v3[j];
        }
        const unsigned short* gp = gvb + ((size_t)b * 64 + n) * 384 + h * 32;
        v0 = *(const u16x8*)(gp);
        v1 = *(const u16x8*)(gp + 8);
        v2 = *(const u16x8*)(gp + 16);
        v3 = *(const u16x8*)(gp + 24);
#pragma unroll
        for (int j = 0; j < 8; ++j) {
            VT[(0 + j) * 136 + 64 + n]  = v0[j];
            VT[(8 + j) * 136 + 64 + n]  = v1[j];
            VT[(16 + j) * 136 + 64 + n] = v2[j];
            VT[(24 + j) * 136 + 64 + n] = v3[j];
        }
    }

    bf16x8 qf[4];
#pragma unroll
    for (int qt = 0; qt < 4; ++qt) {
        int n = qt * 16 + lo;
        int l = lbase + (n >> 3) * 56 + (n & 7);
        qf[qt] = *(const bf16x8*)(qkv + qkvbase + (size_t)l * 1152 + h * 32 + g * 8);
    }

    f32x4 S[4][8];
#pragma unroll
    for (int qt = 0; qt < 4; ++qt)
#pragma unroll
        for (int t = 0; t < 8; ++t) S[qt][t] = f32x4{0.f, 0.f, 0.f, 0.f};

#pragma unroll
    for (int t = 0; t < 8; ++t) {
        bf16x8 kf;
        if (t < 4) {
            int key = t * 16 + lo;
            int l = lbase + (key >> 3) * 56 + (key & 7);
            kf = *(const bf16x8*)(qkv + qkvbase + (size_t)l * 1152 + 384 + h * 32 + g * 8);
        } else {
            int gkey = (t - 4) * 16 + lo;
            kf = *(const bf16x8*)(gkb + ((size_t)b * 64 + gkey) * 384 + h * 32 + g * 8);
        }
#pragma unroll
        for (int qt = 0; qt < 4; ++qt)
            S[qt][t] = __builtin_amdgcn_mfma_f32_16x16x32_bf16(qf[qt], kf, S[qt][t], 0, 0, 0);
    }

    const float* rb_h = rpb_mat + (size_t)h * 4096;
    float mx[4][4];
#pragma unroll
    for (int qt = 0; qt < 4; ++qt)
#pragma unroll
        for (int j = 0; j < 4; ++j) mx[qt][j] = -1e30f;

#pragma unroll
    for (int qt = 0; qt < 4; ++qt) {
#pragma unroll
        for (int t = 0; t < 8; ++t) {
#pragma unroll
            for (int j = 0; j < 4; ++j) {
                float v = S[qt][t][j] * SCALE_ATT;
                if (t < 4) v += rb_h[(qt * 16 + g * 4 + j) * 64 + t * 16 + lo];
                S[qt][t][j] = v;
                mx[qt][j] = fmaxf(mx[qt][j], v);
            }
        }
    }
#pragma unroll
    for (int qt = 0; qt < 4; ++qt)
#pragma unroll
        for (int j = 0; j < 4; ++j) {
#pragma unroll
            for (int m = 1; m <= 8; m <<= 1)
                mx[qt][j] = fmaxf(mx[qt][j], __shfl_xor(mx[qt][j], m));
        }

    float sm[4][4];
#pragma unroll
    for (int qt = 0; qt < 4; ++qt)
#pragma unroll
        for (int j = 0; j < 4; ++j) sm[qt][j] = 0.f;
#pragma unroll
    for (int qt = 0; qt < 4; ++qt)
#pragma unroll
        for (int t = 0; t < 8; ++t)
#pragma unroll
            for (int j = 0; j < 4; ++j) {
                float p = __expf(S[qt][t][j] - mx[qt][j]);
                S[qt][t][j] = p;
                sm[qt][j] += p;
            }
#pragma unroll
    for (int qt = 0; qt < 4; ++qt)
#pragma unroll
        for (int j = 0; j < 4; ++j) {
#pragma unroll
            for (int m = 1; m <= 8; m <<= 1)
                sm[qt][j] += __shfl_xor(sm[qt][j], m);
        }
    float inv[4][4];
#pragma unroll
    for (int qt = 0; qt < 4; ++qt)
#pragma unroll
        for (int j = 0; j < 4; ++j) inv[qt][j] = 1.f / sm[qt][j];

    f32x4 O[4][2];
#pragma unroll
    for (int qt = 0; qt < 4; ++qt)
#pragma unroll
        for (int dt = 0; dt < 2; ++dt) O[qt][dt] = f32x4{0.f, 0.f, 0.f, 0.f};

#pragma unroll
    for (int c = 0; c < 4; ++c) {
        __syncthreads();
#pragma unroll
        for (int qt = 0; qt < 4; ++qt) {
            int qb = qt * 16 + g * 4;
#pragma unroll
            for (int half = 0; half < 2; ++half) {
                int t = 2 * c + half;
#pragma unroll
                for (int j = 0; j < 4; ++j)
                    PL[(qb + j) * 40 + half * 16 + lo] = f2b_fast(S[qt][t][j]);
            }
        }
        __syncthreads();
#pragma unroll
        for (int qt = 0; qt < 4; ++qt) {
            bf16x8 pa = *(const bf16x8*)(PL + (qt * 16 + lo) * 40 + g * 8);
#pragma unroll
            for (int dt = 0; dt < 2; ++dt) {
                bf16x8 vb = *(const bf16x8*)(VT + (dt * 16 + lo) * 136 + c * 32 + g * 8);
                O[qt][dt] = __builtin_amdgcn_mfma_f32_16x16x32_bf16(pa, vb, O[qt][dt], 0, 0, 0);
            }
        }
    }

#pragma unroll
    for (int qt = 0; qt < 4; ++qt)
#pragma unroll
        for (int dt = 0; dt < 2; ++dt)
#pragma unroll
            for (int j = 0; j < 4; ++j) {
                int q = qt * 16 + g * 4 + j;
                int d = dt * 16 + lo;
                ow[((size_t)wg * 64 + q) * 384 + h * 32 + d] = f2b_fast(O[qt][dt][j] * inv[qt][j]);
            }
}

// ---------------- workspace layout (bytes) ----------------
static const size_t OFF_XN   = 0;             // ushort 50176*384   (later: ln2out)
static const size_t OFF_QKV  = 38535168;      // ushort 50176*1152  (later: h)
static const size_t OFF_OW   = 154140672;     // ushort 50176*384
static const size_t OFF_X2   = 192675840;     // float  50176*384
static const size_t OFF_PL   = 269746176;     // float  784*384 (pooled; later: rpb_mat)
static const size_t OFF_KEY  = 270950400;     // float  784*384
static const size_t OFF_VAL  = 272154624;     // float  784*384
static const size_t OFF_O    = 273358848;     // float  1024*384
static const size_t OFF_GK   = 274931712;     // ushort 1024*384
static const size_t OFF_GV   = 276504576;     // ushort 1024*384
static const size_t OFF_QKVW = 278077440;     // ushort 1152*384 (W^T [N][K])
static const size_t OFF_PRJW = 278962176;     // ushort 384*384
static const size_t OFF_FC1W = 279257088;     // ushort 1536*384
static const size_t OFF_FC2W = 280436736;     // ushort 384*1536   (end: 281,616,384)

extern "C" void kernel_launch(void* const* d_in, const int* in_sizes, int n_in,
                              void* d_out, int out_size, void* d_ws, size_t ws_size,
                              hipStream_t stream) {
    const float* x      = (const float*)d_in[0];
    const float* qtok   = (const float*)d_in[1];
    const float* kprojw = (const float*)d_in[2];
    const float* kprojb = (const float*)d_in[3];
    const float* kbng   = (const float*)d_in[4];
    const float* kbnb   = (const float*)d_in[5];
    const float* vprojw = (const float*)d_in[6];
    const float* vprojb = (const float*)d_in[7];
    const float* vbng   = (const float*)d_in[8];
    const float* vbnb   = (const float*)d_in[9];
    const float* ckw    = (const float*)d_in[10];
    const float* ckb    = (const float*)d_in[11];
    const float* cvw    = (const float*)d_in[12];
    const float* cvb    = (const float*)d_in[13];
    const float* qkvw   = (const float*)d_in[14];
    const float* qkvb   = (const float*)d_in[15];
    const float* projw  = (const float*)d_in[16];
    const float* projb  = (const float*)d_in[17];
    const float* rpbt   = (const float*)d_in[18];
    const float* n1g    = (const float*)d_in[19];
    const float* n1b    = (const float*)d_in[20];
    const float* n2g    = (const float*)d_in[21];
    const float* n2b    = (const float*)d_in[22];
    const float* fc1w   = (const float*)d_in[23];
    const float* fc1b   = (const float*)d_in[24];
    const float* fc2w   = (const float*)d_in[25];
    const float* fc2b   = (const float*)d_in[26];

    char* wsb = (char*)d_ws;
    unsigned short* xn     = (unsigned short*)(wsb + OFF_XN);
    unsigned short* qkvbf  = (unsigned short*)(wsb + OFF_QKV);
    unsigned short* owbf   = (unsigned short*)(wsb + OFF_OW);
    float* x2      = (float*)(wsb + OFF_X2);
    float* pooled  = (float*)(wsb + OFF_PL);
    float* rpb_mat = (float*)(wsb + OFF_PL);
    float* keyg    = (float*)(wsb + OFF_KEY);
    float* valg    = (float*)(wsb + OFF_VAL);
    float* obuf    = (float*)(wsb + OFF_O);
    unsigned short* gkb = (unsigned short*)(wsb + OFF_GK);
    unsigned short* gvb = (unsigned short*)(wsb + OFF_GV);
    unsigned short* qkvw_t = (unsigned short*)(wsb + OFF_QKVW);
    unsigned short* prjw_t = (unsigned short*)(wsb + OFF_PRJW);
    unsigned short* fc1w_t = (unsigned short*)(wsb + OFF_FC1W);
    unsigned short* fc2w_t = (unsigned short*)(wsb + OFF_FC2W);
    unsigned short* ln2out = (unsigned short*)(wsb + OFF_XN);     // reuse xn
    unsigned short* hbuf   = (unsigned short*)(wsb + OFF_QKV);    // reuse qkv(+ow)

    // 0. convert + transpose all 4 weights to bf16 [N][K] (one launch)
    cvt_all<<<6912, 256, 0, stream>>>(qkvw, projw, fc1w, fc2w, qkvw_t, prjw_t, fc1w_t, fc2w_t);
    // 1. LN1
    ln_kernel<<<50176, 64, 0, stream>>>(x, n1g, n1b, xn);
    // 2. pool + k/v proj
    pool_kernel<<<784, 384, 0, stream>>>(xn, pooled);
    kvproj_kernel<<<784, 128, 0, stream>>>(pooled, kprojw, kprojb, kbng, kbnb,
                                           vprojw, vprojb, vbng, vbnb, keyg, valg);
    // 2b. rpb dense expand
    rpb_expand_kernel<<<768, 64, 0, stream>>>(rpbt, rpb_mat);
    // 3. cross attention
    cross_attn_kernel<<<192, 64, 0, stream>>>(keyg, valg, qtok, obuf);
    // 4. gk/gv
    gkv_kernel<<<1024, 128, 0, stream>>>(obuf, qtok, ckw, ckb, cvw, cvb, gkb, gvb);
    // 5. qkv GEMM  [50176 x 1152 x 384]
    gemm128<0><<<dim3(9, 392), 256, 0, stream>>>(xn, qkvw_t, qkvb, 1152, 384, qkvbf, nullptr);
    // 6. windowed attention (MFMA)
    win_attn_mfma<<<9408, 64, 0, stream>>>(qkvbf, gkb, gvb, rpb_mat, owbf);
    // 7. proj GEMM + window reverse + residual -> x2 (fp32)
    gemm128<1><<<dim3(3, 392), 256, 0, stream>>>(owbf, prjw_t, projb, 384, 384, x2, x);
    // 8. LN2 -> bf16 scratch
    ln_kernel<<<50176, 64, 0, stream>>>(x2, n2g, n2b, ln2out);
    // 9. fc1 + GELU  [50176 x 1536 x 384]
    gemm128<2><<<dim3(12, 392), 256, 0, stream>>>(ln2out, fc1w_t, fc1b, 1536, 384, hbuf, nullptr);
    // 10. fc2 + residual  [50176 x 384 x 1536] -> fp32 d_out
    gemm128<3><<<dim3(3, 392), 256, 0, stream>>>(hbuf, fc2w_t, fc2b, 384, 1536, (float*)d_out, x2);
}

// Round 16
// 754.159 us; speedup vs baseline: 1.0769x; 1.0769x over previous
//
#include <hip/hip_runtime.h>
#include <math.h>

typedef __attribute__((ext_vector_type(8))) __bf16 bf16x8;
typedef __attribute__((ext_vector_type(4))) float f32x4;
typedef __attribute__((ext_vector_type(8))) unsigned short u16x8;

#define DI __device__ __forceinline__

DI float b2f(unsigned short u) { return __uint_as_float(((unsigned int)u) << 16); }
DI unsigned short f2b(float f) {
    unsigned int x = __float_as_uint(f);
    x += 0x7fffu + ((x >> 16) & 1u);   // round-to-nearest-even
    return (unsigned short)(x >> 16);
}
DI unsigned short f2b_fast(float f) {
    __bf16 h = (__bf16)f;
    return *(unsigned short*)&h;
}

// async global -> LDS, 16 B per lane (dest = wave-uniform base + lane*16)
DI void gl16(const unsigned short* g, unsigned short* l) {
    __builtin_amdgcn_global_load_lds(
        (const __attribute__((address_space(1))) void*)g,
        (__attribute__((address_space(3))) void*)l,
        16, 0, 0);
}

// tanh-GELU, algebraic: 0.5v(1+tanh(u)) == v * sigmoid(2u)
DI float gelu_f(float v) {
    float y = -1.5957691216f * v - 0.0713548163f * v * v * v;   // -2u
    return v * __builtin_amdgcn_rcpf(1.f + __expf(y));
}

// B=16, H=W=56, L=3136, C=384, NH=12, HD=32, WS=8, nW=49, N=64, NQ=64, MLP_H=1536
#define SCALE_ATT 0.17677669529663687f
#define BN_SCALE  0.9999950000374997f   // 1/sqrt(1+1e-5)

// ---------------- merged fp32 [K][N] -> bf16 [N][K] for all 4 weights ----------------
__global__ __launch_bounds__(256) void cvt_all(const float* __restrict__ s0, const float* __restrict__ s1,
                                               const float* __restrict__ s2, const float* __restrict__ s3,
                                               unsigned short* __restrict__ d0, unsigned short* __restrict__ d1,
                                               unsigned short* __restrict__ d2, unsigned short* __restrict__ d3) {
    int b = blockIdx.x;
    const float* in;
    unsigned short* out;
    int Kd, Nd, i0;
    if (b < 1728)      { in = s0; out = d0; Kd = 384;  Nd = 1152; i0 = b * 256; }
    else if (b < 2304) { in = s1; out = d1; Kd = 384;  Nd = 384;  i0 = (b - 1728) * 256; }
    else if (b < 4608) { in = s2; out = d2; Kd = 384;  Nd = 1536; i0 = (b - 2304) * 256; }
    else               { in = s3; out = d3; Kd = 1536; Nd = 384;  i0 = (b - 4608) * 256; }
    int i = i0 + threadIdx.x;
    if (i < Kd * Nd) {
        int k = i / Nd, n = i % Nd;
        out[(size_t)n * Kd + k] = f2b(in[i]);
    }
}

// ---------------- LayerNorm (row = 384), fp32 in -> bf16 out, vectorized ----------------
__global__ __launch_bounds__(64) void ln_kernel(const float* __restrict__ xin,
                                                const float* __restrict__ g,
                                                const float* __restrict__ bsh,
                                                unsigned short* __restrict__ out) {
    int row = blockIdx.x;
    int t = threadIdx.x;
    size_t base = (size_t)row * 384;
    float2 v[3];
    float s = 0.f, q = 0.f;
#pragma unroll
    for (int p = 0; p < 3; ++p) {
        v[p] = *(const float2*)(xin + base + p * 128 + t * 2);
        s += v[p].x + v[p].y;
        q += v[p].x * v[p].x + v[p].y * v[p].y;
    }
#pragma unroll
    for (int off = 32; off > 0; off >>= 1) {
        s += __shfl_xor(s, off);
        q += __shfl_xor(q, off);
    }
    float mu = s * (1.f / 384.f);
    float rstd = rsqrtf(q * (1.f / 384.f) - mu * mu + 1e-5f);
#pragma unroll
    for (int p = 0; p < 3; ++p) {
        int c = p * 128 + t * 2;
        unsigned int lo16 = f2b((v[p].x - mu) * rstd * g[c] + bsh[c]);
        unsigned int hi16 = f2b((v[p].y - mu) * rstd * g[c + 1] + bsh[c + 1]);
        ((unsigned int*)(out + base + p * 128))[t] = lo16 | (hi16 << 16);
    }
}

// ---------------- 8x8 average pool ----------------
__global__ __launch_bounds__(384) void pool_kernel(const unsigned short* __restrict__ xn,
                                                   float* __restrict__ pooled) {
    int blk = blockIdx.x;
    int b = blk / 49, pp = blk % 49;
    int ph = pp / 7, pw = pp % 7;
    int c = threadIdx.x;
    float s = 0.f;
    for (int i = 0; i < 8; ++i) {
        size_t rb = ((size_t)b * 3136 + (size_t)(ph * 8 + i) * 56 + pw * 8) * 384;
        for (int j = 0; j < 8; ++j) s += b2f(xn[rb + (size_t)j * 384 + c]);
    }
    pooled[(size_t)blk * 384 + c] = s * (1.f / 64.f);
}

// ---------------- key/value conv1x1 + BN ----------------
__global__ __launch_bounds__(128) void kvproj_kernel(
    const float* __restrict__ pooled,
    const float* __restrict__ kw, const float* __restrict__ kb,
    const float* __restrict__ kg, const float* __restrict__ kbb,
    const float* __restrict__ vw, const float* __restrict__ vb,
    const float* __restrict__ vg, const float* __restrict__ vbb,
    float* __restrict__ keyo, float* __restrict__ valo) {
    __shared__ float row[384];
    int r = blockIdx.x;
    int t = threadIdx.x;
    for (int c = t; c < 384; c += 128) row[c] = pooled[(size_t)r * 384 + c];
    __syncthreads();
#pragma unroll
    for (int p = 0; p < 3; ++p) {
        int c = t + 128 * p;
        float aK = 0.f, aV = 0.f;
        for (int k = 0; k < 384; ++k) {
            float rv = row[k];
            aK += rv * kw[(size_t)k * 384 + c];
            aV += rv * vw[(size_t)k * 384 + c];
        }
        keyo[(size_t)r * 384 + c] = (aK + kb[c]) * BN_SCALE * kg[c] + kbb[c];
        valo[(size_t)r * 384 + c] = (aV + vb[c]) * BN_SCALE * vg[c] + vbb[c];
    }
}

// ---------------- rel-pos bias expand ----------------
__global__ __launch_bounds__(64) void rpb_expand_kernel(const float* __restrict__ rpbt,
                                                        float* __restrict__ rpb_mat) {
    int h = blockIdx.x >> 6, q = blockIdx.x & 63;
    int k = threadIdx.x;
    int i1 = q >> 3, j1 = q & 7, i2 = k >> 3, j2 = k & 7;
    rpb_mat[((size_t)h * 64 + q) * 64 + k] = rpbt[(size_t)((i1 - i2 + 7) * 15 + (j1 - j2 + 7)) * 12 + h];
}

// ---------------- global cross attention ----------------
__global__ __launch_bounds__(64) void cross_attn_kernel(const float* __restrict__ keyg,
                                                        const float* __restrict__ valg,
                                                        const float* __restrict__ qtok,
                                                        float* __restrict__ o) {
    int b = blockIdx.x / 12, h = blockIdx.x % 12;
    __shared__ float kk[49][32];
    __shared__ float vv[49][32];
    int t = threadIdx.x;
    for (int idx = t; idx < 49 * 32; idx += 64) {
        int k = idx >> 5, d = idx & 31;
        size_t gidx = ((size_t)b * 49 + k) * 384 + h * 32 + d;
        kk[k][d] = keyg[gidx];
        vv[k][d] = valg[gidx];
    }
    __syncthreads();
    float q[32];
#pragma unroll
    for (int d = 0; d < 32; ++d) q[d] = qtok[(size_t)t * 384 + h * 32 + d] * SCALE_ATT;
    float lg[49];
    float mx = -1e30f;
#pragma unroll
    for (int k = 0; k < 49; ++k) {
        float s = 0.f;
#pragma unroll
        for (int d = 0; d < 32; ++d) s += q[d] * kk[k][d];
        lg[k] = s;
        mx = fmaxf(mx, s);
    }
    float sum = 0.f;
#pragma unroll
    for (int k = 0; k < 49; ++k) { float e = expf(lg[k] - mx); lg[k] = e; sum += e; }
    float inv = 1.f / sum;
    float od[32];
#pragma unroll
    for (int d = 0; d < 32; ++d) od[d] = 0.f;
#pragma unroll
    for (int k = 0; k < 49; ++k) {
        float wgt = lg[k];
#pragma unroll
        for (int d = 0; d < 32; ++d) od[d] += wgt * vv[k][d];
    }
#pragma unroll
    for (int d = 0; d < 32; ++d) o[((size_t)b * 64 + t) * 384 + h * 32 + d] = od[d] * inv;
}

// ---------------- gk/gv ----------------
__global__ __launch_bounds__(128) void gkv_kernel(
    const float* __restrict__ o, const float* __restrict__ qtok,
    const float* __restrict__ ckw, const float* __restrict__ ckb,
    const float* __restrict__ cvw, const float* __restrict__ cvb,
    unsigned short* __restrict__ gk, unsigned short* __restrict__ gv) {
    __shared__ float row[384];
    int r = blockIdx.x;
    int n = r & 63;
    int t = threadIdx.x;
    for (int c = t; c < 384; c += 128)
        row[c] = o[(size_t)r * 384 + c] + qtok[(size_t)n * 384 + c];
    __syncthreads();
#pragma unroll
    for (int p = 0; p < 3; ++p) {
        int c = t + 128 * p;
        float aK = 0.f, aV = 0.f;
        for (int k = 0; k < 384; ++k) {
            float rv = row[k];
            aK += rv * ckw[(size_t)k * 384 + c];
            aV += rv * cvw[(size_t)k * 384 + c];
        }
        gk[(size_t)r * 384 + c] = f2b(aK + ckb[c]);
        gv[(size_t)r * 384 + c] = f2b(aV + cvb[c]);
    }
}

// ---------------- MFMA GEMM, 128x128 tile, 4 waves, 4-buffer 3-deep counted-vmcnt ----------------
// r14 structure with pipeline depth 2->3: 4 LDS buffers (64KB, 2 blocks/CU), prologue stages
// 3 tiles, steady wait vmcnt(8) (keep 2 stages in flight), tail ladder vmcnt(4)/vmcnt(0).
// T2 chunk swizzle pc = c ^ ((row>>1)&3) on global source; read-side XOR; 0 conflicts (r9).
template <int MODE>
__global__ __launch_bounds__(256, 2) void gemm128(const unsigned short* __restrict__ A,
                                                  const unsigned short* __restrict__ BT,
                                                  const float* __restrict__ bias,
                                                  int N, int K,
                                                  void* __restrict__ outp,
                                                  const void* __restrict__ aux0) {
    __shared__ __align__(16) unsigned short As[4][128 * 32];
    __shared__ __align__(16) unsigned short Bs[4][128 * 32];

    // XCD-aware bijective swizzle
    int nwg = gridDim.x * gridDim.y;
    int flat = blockIdx.y * gridDim.x + blockIdx.x;
    int flat2 = (flat & 7) * (nwg >> 3) + (flat >> 3);
    int bn = flat2 % gridDim.x, bm = flat2 / gridDim.x;

    int t = threadIdx.x;
    int w = t >> 6, lane = t & 63;
    int wm = w >> 1, wn = w & 1;
    int lo = lane & 15, g = lane >> 4;

    f32x4 acc[4][4];
#pragma unroll
    for (int i = 0; i < 4; ++i)
#pragma unroll
        for (int j = 0; j < 4; ++j) acc[i][j] = f32x4{0.f, 0.f, 0.f, 0.f};

    int srow = w * 32 + (lane >> 2);
    int schunk = (((lane & 3) ^ ((srow >> 1) & 3)) << 3);   // swizzled global k-chunk
    const unsigned short* Ap0 = A + (size_t)(bm * 128 + srow) * K + schunk;
    const unsigned short* Ap1 = A + (size_t)(bm * 128 + srow + 16) * K + schunk;
    const unsigned short* Bp0 = BT + (size_t)(bn * 128 + srow) * K + schunk;
    const unsigned short* Bp1 = BT + (size_t)(bn * 128 + srow + 16) * K + schunk;
    int d0 = (w * 32) * 32, d1 = (w * 32 + 16) * 32;

    int gx = ((g ^ ((lo >> 1) & 3)) << 3);

#define STAGE(buf, kb)                    \
    do {                                  \
        gl16(Ap0 + (kb), As[buf] + d0);   \
        gl16(Ap1 + (kb), As[buf] + d1);   \
        gl16(Bp0 + (kb), Bs[buf] + d0);   \
        gl16(Bp1 + (kb), Bs[buf] + d1);   \
    } while (0)

#define WAIT8() asm volatile("s_waitcnt vmcnt(8)" ::: "memory")
#define WAIT4() asm volatile("s_waitcnt vmcnt(4)" ::: "memory")
#define WAIT0() asm volatile("s_waitcnt vmcnt(0)" ::: "memory")
// phase for tile k: if (k+2<nt) WAIT8 else if (k+1<nt) WAIT4 else WAIT0
#define WAITK(k)                             \
    do {                                     \
        if ((k) + 2 < nt) WAIT8();           \
        else if ((k) + 1 < nt) WAIT4();      \
        else WAIT0();                        \
    } while (0)

#define COMPUTE(buf)                                                                     \
    do {                                                                                 \
        bf16x8 af[4], bfv[4];                                                            \
        _Pragma("unroll")                                                                \
        for (int m = 0; m < 4; ++m)                                                      \
            af[m] = *(const bf16x8*)(As[buf] + (wm * 64 + m * 16 + lo) * 32 + gx);       \
        _Pragma("unroll")                                                                \
        for (int n = 0; n < 4; ++n)                                                      \
            bfv[n] = *(const bf16x8*)(Bs[buf] + (wn * 64 + n * 16 + lo) * 32 + gx);      \
        __builtin_amdgcn_s_setprio(1);                                                   \
        _Pragma("unroll")                                                                \
        for (int m = 0; m < 4; ++m)                                                      \
            _Pragma("unroll")                                                            \
            for (int n = 0; n < 4; ++n)                                                  \
                acc[m][n] = __builtin_amdgcn_mfma_f32_16x16x32_bf16(af[m], bfv[n],       \
                                                                    acc[m][n], 0, 0, 0); \
        __builtin_amdgcn_s_setprio(0);                                                   \
    } while (0)

    // prologue: 3 tiles in flight (12 outstanding vm ops per wave)
    STAGE(0, 0);
    STAGE(1, 32);
    STAGE(2, 64);

    int nt = K >> 5;   // 12 or 48 -> divisible by 4
    for (int tt = 0; tt < nt; tt += 4) {
        // tile tt (buf 0); stage tile tt+3 into buf 3
        WAITK(tt);
        __builtin_amdgcn_s_barrier();
        if (tt + 3 < nt) STAGE(3, (tt + 3) * 32);
        COMPUTE(0);
        // tile tt+1 (buf 1); stage tile tt+4 into buf 0
        WAITK(tt + 1);
        __builtin_amdgcn_s_barrier();
        if (tt + 4 < nt) STAGE(0, (tt + 4) * 32);
        COMPUTE(1);
        // tile tt+2 (buf 2); stage tile tt+5 into buf 1
        WAITK(tt + 2);
        __builtin_amdgcn_s_barrier();
        if (tt + 5 < nt) STAGE(1, (tt + 5) * 32);
        COMPUTE(2);
        // tile tt+3 (buf 3); stage tile tt+6 into buf 2
        WAITK(tt + 3);
        __builtin_amdgcn_s_barrier();
        if (tt + 6 < nt) STAGE(2, (tt + 6) * 32);
        COMPUTE(3);
    }
#undef STAGE
#undef WAIT8
#undef WAIT4
#undef WAIT0
#undef WAITK
#undef COMPUTE

    int r0 = bm * 128 + wm * 64 + g * 4;
    int c0 = bn * 128 + wn * 64 + lo;
    // MODE 1 hoist: r>>6 == bm*2+wm (thread-constant since m*16+g*4+j < 64)
    int wgc = bm * 2 + wm;
    int bC = wgc / 49, winC = wgc % 49;
    int whC = winC / 7, wwC = winC % 7;
    int lC = (whC << 3) * 56 + (wwC << 3);
    size_t rowbaseC = (size_t)bC * 3136;
#pragma unroll
    for (int m = 0; m < 4; ++m)
#pragma unroll
        for (int n = 0; n < 4; ++n)
#pragma unroll
            for (int j = 0; j < 4; ++j) {
                int r = r0 + m * 16 + j;
                int c = c0 + n * 16;
                float v = acc[m][n][j] + bias[c];
                if (MODE == 0) {
                    ((unsigned short*)outp)[(size_t)r * N + c] = f2b(v);
                } else if (MODE == 1) {
                    int nn = m * 16 + (g << 2) + j;          // r & 63
                    int l = lC + (nn >> 3) * 56 + (nn & 7);
                    size_t idx = (rowbaseC + l) * 384 + c;
                    ((float*)outp)[idx] = ((const float*)aux0)[idx] + v;
                } else if (MODE == 2) {
                    ((unsigned short*)outp)[(size_t)r * N + c] = f2b(gelu_f(v));
                } else {
                    float res = ((const float*)aux0)[(size_t)r * 384 + c];
                    ((float*)outp)[(size_t)r * N + c] = v + res;
                }
            }
}

// ---------------- MFMA windowed attention: one wave per (window, head) ----------------
__global__ __launch_bounds__(64, 2) void win_attn_mfma(const unsigned short* __restrict__ qkv,
                                                       const unsigned short* __restrict__ gkb,
                                                       const unsigned short* __restrict__ gvb,
                                                       const float* __restrict__ rpb_mat,
                                                       unsigned short* __restrict__ ow) {
    int blk = blockIdx.x;
    int wg = blk / 12, h = blk % 12;
    int b = wg / 49, win = wg % 49;
    int wh = win / 7, ww = win % 7;
    int lane = threadIdx.x;
    int lo = lane & 15, g = lane >> 4;

    __shared__ __align__(16) unsigned short VT[32 * 136];
    __shared__ __align__(16) unsigned short PL[64 * 40];

    size_t qkvbase = (size_t)b * 3136 * 1152;
    int lbase = ((wh << 3)) * 56 + (ww << 3);

    {
        int n = lane;
        int l = lbase + (n >> 3) * 56 + (n & 7);
        const unsigned short* vp = qkv + qkvbase + (size_t)l * 1152 + 768 + h * 32;
        u16x8 v0 = *(const u16x8*)(vp);
        u16x8 v1 = *(const u16x8*)(vp + 8);
        u16x8 v2 = *(const u16x8*)(vp + 16);
        u16x8 v3 = *(const u16x8*)(vp + 24);
#pragma unroll
        for (int j = 0; j < 8; ++j) {
            VT[(0 + j) * 136 + n]  = v0[j];
            VT[(8 + j) * 136 + n]  = v1[j];
            VT[(16 + j) * 136 + n] = v2[j];
            VT[(24 + j) * 136 + n] = v3[j];
        }
        const unsigned short* gp = gvb + ((size_t)b * 64 + n) * 384 + h * 32;
        v0 = *(const u16x8*)(gp);
        v1 = *(const u16x8*)(gp + 8);
        v2 = *(const u16x8*)(gp + 16);
        v3 = *(const u16x8*)(gp + 24);
#pragma unroll
        for (int j = 0; j < 8; ++j) {
            VT[(0 + j) * 136 + 64 + n]  = v0[j];
            VT[(8 + j) * 136 + 64 + n]  = v1[j];
            VT[(16 + j) * 136 + 64 + n] = v2[j];
            VT[(24 + j) * 136 + 64 + n] = v3[j];
        }
    }

    bf16x8 qf[4];
#pragma unroll
    for (int qt = 0; qt < 4; ++qt) {
        int n = qt * 16 + lo;
        int l = lbase + (n >> 3) * 56 + (n & 7);
        qf[qt] = *(const bf16x8*)(qkv + qkvbase + (size_t)l * 1152 + h * 32 + g * 8);
    }

    f32x4 S[4][8];
#pragma unroll
    for (int qt = 0; qt < 4; ++qt)
#pragma unroll
        for (int t = 0; t < 8; ++t) S[qt][t] = f32x4{0.f, 0.f, 0.f, 0.f};

#pragma unroll
    for (int t = 0; t < 8; ++t) {
        bf16x8 kf;
        if (t < 4) {
            int key = t * 16 + lo;
            int l = lbase + (key >> 3) * 56 + (key & 7);
            kf = *(const bf16x8*)(qkv + qkvbase + (size_t)l * 1152 + 384 + h * 32 + g * 8);
        } else {
            int gkey = (t - 4) * 16 + lo;
            kf = *(const bf16x8*)(gkb + ((size_t)b * 64 + gkey) * 384 + h * 32 + g * 8);
        }
#pragma unroll
        for (int qt = 0; qt < 4; ++qt)
            S[qt][t] = __builtin_amdgcn_mfma_f32_16x16x32_bf16(qf[qt], kf, S[qt][t], 0, 0, 0);
    }

    const float* rb_h = rpb_mat + (size_t)h * 4096;
    float mx[4][4];
#pragma unroll
    for (int qt = 0; qt < 4; ++qt)
#pragma unroll
        for (int j = 0; j < 4; ++j) mx[qt][j] = -1e30f;

#pragma unroll
    for (int qt = 0; qt < 4; ++qt) {
#pragma unroll
        for (int t = 0; t < 8; ++t) {
#pragma unroll
            for (int j = 0; j < 4; ++j) {
                float v = S[qt][t][j] * SCALE_ATT;
                if (t < 4) v += rb_h[(qt * 16 + g * 4 + j) * 64 + t * 16 + lo];
                S[qt][t][j] = v;
                mx[qt][j] = fmaxf(mx[qt][j], v);
            }
        }
    }
#pragma unroll
    for (int qt = 0; qt < 4; ++qt)
#pragma unroll
        for (int j = 0; j < 4; ++j) {
#pragma unroll
            for (int m = 1; m <= 8; m <<= 1)
                mx[qt][j] = fmaxf(mx[qt][j], __shfl_xor(mx[qt][j], m));
        }

    float sm[4][4];
#pragma unroll
    for (int qt = 0; qt < 4; ++qt)
#pragma unroll
        for (int j = 0; j < 4; ++j) sm[qt][j] = 0.f;
#pragma unroll
    for (int qt = 0; qt < 4; ++qt)
#pragma unroll
        for (int t = 0; t < 8; ++t)
#pragma unroll
            for (int j = 0; j < 4; ++j) {
                float p = __expf(S[qt][t][j] - mx[qt][j]);
                S[qt][t][j] = p;
                sm[qt][j] += p;
            }
#pragma unroll
    for (int qt = 0; qt < 4; ++qt)
#pragma unroll
        for (int j = 0; j < 4; ++j) {
#pragma unroll
            for (int m = 1; m <= 8; m <<= 1)
                sm[qt][j] += __shfl_xor(sm[qt][j], m);
        }
    float inv[4][4];
#pragma unroll
    for (int qt = 0; qt < 4; ++qt)
#pragma unroll
        for (int j = 0; j < 4; ++j) inv[qt][j] = 1.f / sm[qt][j];

    f32x4 O[4][2];
#pragma unroll
    for (int qt = 0; qt < 4; ++qt)
#pragma unroll
        for (int dt = 0; dt < 2; ++dt) O[qt][dt] = f32x4{0.f, 0.f, 0.f, 0.f};

#pragma unroll
    for (int c = 0; c < 4; ++c) {
        __syncthreads();
#pragma unroll
        for (int qt = 0; qt < 4; ++qt) {
            int qb = qt * 16 + g * 4;
#pragma unroll
            for (int half = 0; half < 2; ++half) {
                int t = 2 * c + half;
#pragma unroll
                for (int j = 0; j < 4; ++j)
                    PL[(qb + j) * 40 + half * 16 + lo] = f2b_fast(S[qt][t][j]);
            }
        }
        __syncthreads();
#pragma unroll
        for (int qt = 0; qt < 4; ++qt) {
            bf16x8 pa = *(const bf16x8*)(PL + (qt * 16 + lo) * 40 + g * 8);
#pragma unroll
            for (int dt = 0; dt < 2; ++dt) {
                bf16x8 vb = *(const bf16x8*)(VT + (dt * 16 + lo) * 136 + c * 32 + g * 8);
                O[qt][dt] = __builtin_amdgcn_mfma_f32_16x16x32_bf16(pa, vb, O[qt][dt], 0, 0, 0);
            }
        }
    }

#pragma unroll
    for (int qt = 0; qt < 4; ++qt)
#pragma unroll
        for (int dt = 0; dt < 2; ++dt)
#pragma unroll
            for (int j = 0; j < 4; ++j) {
                int q = qt * 16 + g * 4 + j;
                int d = dt * 16 + lo;
                ow[((size_t)wg * 64 + q) * 384 + h * 32 + d] = f2b_fast(O[qt][dt][j] * inv[qt][j]);
            }
}

// ---------------- workspace layout (bytes) ----------------
static const size_t OFF_XN   = 0;             // ushort 50176*384   (later: ln2out)
static const size_t OFF_QKV  = 38535168;      // ushort 50176*1152  (later: h)
static const size_t OFF_OW   = 154140672;     // ushort 50176*384
static const size_t OFF_X2   = 192675840;     // float  50176*384
static const size_t OFF_PL   = 269746176;     // float  784*384 (pooled; later: rpb_mat)
static const size_t OFF_KEY  = 270950400;     // float  784*384
static const size_t OFF_VAL  = 272154624;     // float  784*384
static const size_t OFF_O    = 273358848;     // float  1024*384
static const size_t OFF_GK   = 274931712;     // ushort 1024*384
static const size_t OFF_GV   = 276504576;     // ushort 1024*384
static const size_t OFF_QKVW = 278077440;     // ushort 1152*384 (W^T [N][K])
static const size_t OFF_PRJW = 278962176;     // ushort 384*384
static const size_t OFF_FC1W = 279257088;     // ushort 1536*384
static const size_t OFF_FC2W = 280436736;     // ushort 384*1536   (end: 281,616,384)

extern "C" void kernel_launch(void* const* d_in, const int* in_sizes, int n_in,
                              void* d_out, int out_size, void* d_ws, size_t ws_size,
                              hipStream_t stream) {
    const float* x      = (const float*)d_in[0];
    const float* qtok   = (const float*)d_in[1];
    const float* kprojw = (const float*)d_in[2];
    const float* kprojb = (const float*)d_in[3];
    const float* kbng   = (const float*)d_in[4];
    const float* kbnb   = (const float*)d_in[5];
    const float* vprojw = (const float*)d_in[6];
    const float* vprojb = (const float*)d_in[7];
    const float* vbng   = (const float*)d_in[8];
    const float* vbnb   = (const float*)d_in[9];
    const float* ckw    = (const float*)d_in[10];
    const float* ckb    = (const float*)d_in[11];
    const float* cvw    = (const float*)d_in[12];
    const float* cvb    = (const float*)d_in[13];
    const float* qkvw   = (const float*)d_in[14];
    const float* qkvb   = (const float*)d_in[15];
    const float* projw  = (const float*)d_in[16];
    const float* projb  = (const float*)d_in[17];
    const float* rpbt   = (const float*)d_in[18];
    const float* n1g    = (const float*)d_in[19];
    const float* n1b    = (const float*)d_in[20];
    const float* n2g    = (const float*)d_in[21];
    const float* n2b    = (const float*)d_in[22];
    const float* fc1w   = (const float*)d_in[23];
    const float* fc1b   = (const float*)d_in[24];
    const float* fc2w   = (const float*)d_in[25];
    const float* fc2b   = (const float*)d_in[26];

    char* wsb = (char*)d_ws;
    unsigned short* xn     = (unsigned short*)(wsb + OFF_XN);
    unsigned short* qkvbf  = (unsigned short*)(wsb + OFF_QKV);
    unsigned short* owbf   = (unsigned short*)(wsb + OFF_OW);
    float* x2      = (float*)(wsb + OFF_X2);
    float* pooled  = (float*)(wsb + OFF_PL);
    float* rpb_mat = (float*)(wsb + OFF_PL);
    float* keyg    = (float*)(wsb + OFF_KEY);
    float* valg    = (float*)(wsb + OFF_VAL);
    float* obuf    = (float*)(wsb + OFF_O);
    unsigned short* gkb = (unsigned short*)(wsb + OFF_GK);
    unsigned short* gvb = (unsigned short*)(wsb + OFF_GV);
    unsigned short* qkvw_t = (unsigned short*)(wsb + OFF_QKVW);
    unsigned short* prjw_t = (unsigned short*)(wsb + OFF_PRJW);
    unsigned short* fc1w_t = (unsigned short*)(wsb + OFF_FC1W);
    unsigned short* fc2w_t = (unsigned short*)(wsb + OFF_FC2W);
    unsigned short* ln2out = (unsigned short*)(wsb + OFF_XN);     // reuse xn
    unsigned short* hbuf   = (unsigned short*)(wsb + OFF_QKV);    // reuse qkv(+ow)

    // 0. convert + transpose all 4 weights to bf16 [N][K] (one launch)
    cvt_all<<<6912, 256, 0, stream>>>(qkvw, projw, fc1w, fc2w, qkvw_t, prjw_t, fc1w_t, fc2w_t);
    // 1. LN1
    ln_kernel<<<50176, 64, 0, stream>>>(x, n1g, n1b, xn);
    // 2. pool + k/v proj
    pool_kernel<<<784, 384, 0, stream>>>(xn, pooled);
    kvproj_kernel<<<784, 128, 0, stream>>>(pooled, kprojw, kprojb, kbng, kbnb,
                                           vprojw, vprojb, vbng, vbnb, keyg, valg);
    // 2b. rpb dense expand
    rpb_expand_kernel<<<768, 64, 0, stream>>>(rpbt, rpb_mat);
    // 3. cross attention
    cross_attn_kernel<<<192, 64, 0, stream>>>(keyg, valg, qtok, obuf);
    // 4. gk/gv
    gkv_kernel<<<1024, 128, 0, stream>>>(obuf, qtok, ckw, ckb, cvw, cvb, gkb, gvb);
    // 5. qkv GEMM  [50176 x 1152 x 384]
    gemm128<0><<<dim3(9, 392), 256, 0, stream>>>(xn, qkvw_t, qkvb, 1152, 384, qkvbf, nullptr);
    // 6. windowed attention (MFMA)
    win_attn_mfma<<<9408, 64, 0, stream>>>(qkvbf, gkb, gvb, rpb_mat, owbf);
    // 7. proj GEMM + window reverse + residual -> x2 (fp32)
    gemm128<1><<<dim3(3, 392), 256, 0, stream>>>(owbf, prjw_t, projb, 384, 384, x2, x);
    // 8. LN2 -> bf16 scratch
    ln_kernel<<<50176, 64, 0, stream>>>(x2, n2g, n2b, ln2out);
    // 9. fc1 + GELU  [50176 x 1536 x 384]
    gemm128<2><<<dim3(12, 392), 256, 0, stream>>>(ln2out, fc1w_t, fc1b, 1536, 384, hbuf, nullptr);
    // 10. fc2 + residual  [50176 x 384 x 1536] -> fp32 d_out
    gemm128<3><<<dim3(3, 392), 256, 0, stream>>>(hbuf, fc2w_t, fc2b, 384, 1536, (float*)d_out, x2);
}

// Round 17
// 698.183 us; speedup vs baseline: 1.1632x; 1.0802x over previous
//
#include <hip/hip_runtime.h>
#include <math.h>

typedef __attribute__((ext_vector_type(8))) __bf16 bf16x8;
typedef __attribute__((ext_vector_type(4))) float f32x4;
typedef __attribute__((ext_vector_type(8))) unsigned short u16x8;

#define DI __device__ __forceinline__

DI float b2f(unsigned short u) { return __uint_as_float(((unsigned int)u) << 16); }
DI unsigned short f2b(float f) {
    unsigned int x = __float_as_uint(f);
    x += 0x7fffu + ((x >> 16) & 1u);   // round-to-nearest-even
    return (unsigned short)(x >> 16);
}
DI unsigned short f2b_fast(float f) {
    __bf16 h = (__bf16)f;
    return *(unsigned short*)&h;
}

// async global -> LDS, 16 B per lane (dest = wave-uniform base + lane*16)
DI void gl16(const unsigned short* g, unsigned short* l) {
    __builtin_amdgcn_global_load_lds(
        (const __attribute__((address_space(1))) void*)g,
        (__attribute__((address_space(3))) void*)l,
        16, 0, 0);
}

// tanh-GELU, algebraic: 0.5v(1+tanh(u)) == v * sigmoid(2u)
DI float gelu_f(float v) {
    float y = -1.5957691216f * v - 0.0713548163f * v * v * v;   // -2u
    return v * __builtin_amdgcn_rcpf(1.f + __expf(y));
}

// B=16, H=W=56, L=3136, C=384, NH=12, HD=32, WS=8, nW=49, N=64, NQ=64, MLP_H=1536
#define SCALE_ATT 0.17677669529663687f
#define BN_SCALE  0.9999950000374997f   // 1/sqrt(1+1e-5)

// ---------------- merged fp32 [K][N] -> bf16 [N][K] for all 4 weights ----------------
__global__ __launch_bounds__(256) void cvt_all(const float* __restrict__ s0, const float* __restrict__ s1,
                                               const float* __restrict__ s2, const float* __restrict__ s3,
                                               unsigned short* __restrict__ d0, unsigned short* __restrict__ d1,
                                               unsigned short* __restrict__ d2, unsigned short* __restrict__ d3) {
    int b = blockIdx.x;
    const float* in;
    unsigned short* out;
    int Kd, Nd, i0;
    if (b < 1728)      { in = s0; out = d0; Kd = 384;  Nd = 1152; i0 = b * 256; }
    else if (b < 2304) { in = s1; out = d1; Kd = 384;  Nd = 384;  i0 = (b - 1728) * 256; }
    else if (b < 4608) { in = s2; out = d2; Kd = 384;  Nd = 1536; i0 = (b - 2304) * 256; }
    else               { in = s3; out = d3; Kd = 1536; Nd = 384;  i0 = (b - 4608) * 256; }
    int i = i0 + threadIdx.x;
    if (i < Kd * Nd) {
        int k = i / Nd, n = i % Nd;
        out[(size_t)n * Kd + k] = f2b(in[i]);
    }
}

// ---------------- LayerNorm (row = 384), fp32 in -> bf16 out, vectorized ----------------
__global__ __launch_bounds__(64) void ln_kernel(const float* __restrict__ xin,
                                                const float* __restrict__ g,
                                                const float* __restrict__ bsh,
                                                unsigned short* __restrict__ out) {
    int row = blockIdx.x;
    int t = threadIdx.x;
    size_t base = (size_t)row * 384;
    float2 v[3];
    float s = 0.f, q = 0.f;
#pragma unroll
    for (int p = 0; p < 3; ++p) {
        v[p] = *(const float2*)(xin + base + p * 128 + t * 2);
        s += v[p].x + v[p].y;
        q += v[p].x * v[p].x + v[p].y * v[p].y;
    }
#pragma unroll
    for (int off = 32; off > 0; off >>= 1) {
        s += __shfl_xor(s, off);
        q += __shfl_xor(q, off);
    }
    float mu = s * (1.f / 384.f);
    float rstd = rsqrtf(q * (1.f / 384.f) - mu * mu + 1e-5f);
#pragma unroll
    for (int p = 0; p < 3; ++p) {
        int c = p * 128 + t * 2;
        unsigned int lo16 = f2b((v[p].x - mu) * rstd * g[c] + bsh[c]);
        unsigned int hi16 = f2b((v[p].y - mu) * rstd * g[c + 1] + bsh[c + 1]);
        ((unsigned int*)(out + base + p * 128))[t] = lo16 | (hi16 << 16);
    }
}

// ---------------- 8x8 average pool ----------------
__global__ __launch_bounds__(384) void pool_kernel(const unsigned short* __restrict__ xn,
                                                   float* __restrict__ pooled) {
    int blk = blockIdx.x;
    int b = blk / 49, pp = blk % 49;
    int ph = pp / 7, pw = pp % 7;
    int c = threadIdx.x;
    float s = 0.f;
    for (int i = 0; i < 8; ++i) {
        size_t rb = ((size_t)b * 3136 + (size_t)(ph * 8 + i) * 56 + pw * 8) * 384;
        for (int j = 0; j < 8; ++j) s += b2f(xn[rb + (size_t)j * 384 + c]);
    }
    pooled[(size_t)blk * 384 + c] = s * (1.f / 64.f);
}

// ---------------- key/value conv1x1 + BN ----------------
__global__ __launch_bounds__(128) void kvproj_kernel(
    const float* __restrict__ pooled,
    const float* __restrict__ kw, const float* __restrict__ kb,
    const float* __restrict__ kg, const float* __restrict__ kbb,
    const float* __restrict__ vw, const float* __restrict__ vb,
    const float* __restrict__ vg, const float* __restrict__ vbb,
    float* __restrict__ keyo, float* __restrict__ valo) {
    __shared__ float row[384];
    int r = blockIdx.x;
    int t = threadIdx.x;
    for (int c = t; c < 384; c += 128) row[c] = pooled[(size_t)r * 384 + c];
    __syncthreads();
#pragma unroll
    for (int p = 0; p < 3; ++p) {
        int c = t + 128 * p;
        float aK = 0.f, aV = 0.f;
        for (int k = 0; k < 384; ++k) {
            float rv = row[k];
            aK += rv * kw[(size_t)k * 384 + c];
            aV += rv * vw[(size_t)k * 384 + c];
        }
        keyo[(size_t)r * 384 + c] = (aK + kb[c]) * BN_SCALE * kg[c] + kbb[c];
        valo[(size_t)r * 384 + c] = (aV + vb[c]) * BN_SCALE * vg[c] + vbb[c];
    }
}

// ---------------- rel-pos bias expand ----------------
__global__ __launch_bounds__(64) void rpb_expand_kernel(const float* __restrict__ rpbt,
                                                        float* __restrict__ rpb_mat) {
    int h = blockIdx.x >> 6, q = blockIdx.x & 63;
    int k = threadIdx.x;
    int i1 = q >> 3, j1 = q & 7, i2 = k >> 3, j2 = k & 7;
    rpb_mat[((size_t)h * 64 + q) * 64 + k] = rpbt[(size_t)((i1 - i2 + 7) * 15 + (j1 - j2 + 7)) * 12 + h];
}

// ---------------- global cross attention ----------------
__global__ __launch_bounds__(64) void cross_attn_kernel(const float* __restrict__ keyg,
                                                        const float* __restrict__ valg,
                                                        const float* __restrict__ qtok,
                                                        float* __restrict__ o) {
    int b = blockIdx.x / 12, h = blockIdx.x % 12;
    __shared__ float kk[49][32];
    __shared__ float vv[49][32];
    int t = threadIdx.x;
    for (int idx = t; idx < 49 * 32; idx += 64) {
        int k = idx >> 5, d = idx & 31;
        size_t gidx = ((size_t)b * 49 + k) * 384 + h * 32 + d;
        kk[k][d] = keyg[gidx];
        vv[k][d] = valg[gidx];
    }
    __syncthreads();
    float q[32];
#pragma unroll
    for (int d = 0; d < 32; ++d) q[d] = qtok[(size_t)t * 384 + h * 32 + d] * SCALE_ATT;
    float lg[49];
    float mx = -1e30f;
#pragma unroll
    for (int k = 0; k < 49; ++k) {
        float s = 0.f;
#pragma unroll
        for (int d = 0; d < 32; ++d) s += q[d] * kk[k][d];
        lg[k] = s;
        mx = fmaxf(mx, s);
    }
    float sum = 0.f;
#pragma unroll
    for (int k = 0; k < 49; ++k) { float e = expf(lg[k] - mx); lg[k] = e; sum += e; }
    float inv = 1.f / sum;
    float od[32];
#pragma unroll
    for (int d = 0; d < 32; ++d) od[d] = 0.f;
#pragma unroll
    for (int k = 0; k < 49; ++k) {
        float wgt = lg[k];
#pragma unroll
        for (int d = 0; d < 32; ++d) od[d] += wgt * vv[k][d];
    }
#pragma unroll
    for (int d = 0; d < 32; ++d) o[((size_t)b * 64 + t) * 384 + h * 32 + d] = od[d] * inv;
}

// ---------------- gk/gv ----------------
__global__ __launch_bounds__(128) void gkv_kernel(
    const float* __restrict__ o, const float* __restrict__ qtok,
    const float* __restrict__ ckw, const float* __restrict__ ckb,
    const float* __restrict__ cvw, const float* __restrict__ cvb,
    unsigned short* __restrict__ gk, unsigned short* __restrict__ gv) {
    __shared__ float row[384];
    int r = blockIdx.x;
    int n = r & 63;
    int t = threadIdx.x;
    for (int c = t; c < 384; c += 128)
        row[c] = o[(size_t)r * 384 + c] + qtok[(size_t)n * 384 + c];
    __syncthreads();
#pragma unroll
    for (int p = 0; p < 3; ++p) {
        int c = t + 128 * p;
        float aK = 0.f, aV = 0.f;
        for (int k = 0; k < 384; ++k) {
            float rv = row[k];
            aK += rv * ckw[(size_t)k * 384 + c];
            aV += rv * cvw[(size_t)k * 384 + c];
        }
        gk[(size_t)r * 384 + c] = f2b(aK + ckb[c]);
        gv[(size_t)r * 384 + c] = f2b(aV + cvb[c]);
    }
}

// ---------------- MFMA GEMM, 128x128 tile, 4 waves, 3-buffer counted-vmcnt + T2 swizzle ----------------
// Best measured structure (r14, 697us): BK=32, 3 LDS buffers (48KB), prologue stages 2 tiles,
// per tile {vmcnt(4); s_barrier; STAGE(t+2); ds_read + setprio(1) MFMA setprio(0)}.
// Chunk swizzle pc = c ^ ((row>>1)&3) on global source (rule #21), read-side XOR; 0 conflicts (r9).
template <int MODE>
__global__ __launch_bounds__(256, 3) void gemm128(const unsigned short* __restrict__ A,
                                                  const unsigned short* __restrict__ BT,
                                                  const float* __restrict__ bias,
                                                  int N, int K,
                                                  void* __restrict__ outp,
                                                  const void* __restrict__ aux0) {
    __shared__ __align__(16) unsigned short As[3][128 * 32];
    __shared__ __align__(16) unsigned short Bs[3][128 * 32];

    // XCD-aware bijective swizzle
    int nwg = gridDim.x * gridDim.y;
    int flat = blockIdx.y * gridDim.x + blockIdx.x;
    int flat2 = (flat & 7) * (nwg >> 3) + (flat >> 3);
    int bn = flat2 % gridDim.x, bm = flat2 / gridDim.x;

    int t = threadIdx.x;
    int w = t >> 6, lane = t & 63;
    int wm = w >> 1, wn = w & 1;
    int lo = lane & 15, g = lane >> 4;

    f32x4 acc[4][4];
#pragma unroll
    for (int i = 0; i < 4; ++i)
#pragma unroll
        for (int j = 0; j < 4; ++j) acc[i][j] = f32x4{0.f, 0.f, 0.f, 0.f};

    int srow = w * 32 + (lane >> 2);
    int schunk = (((lane & 3) ^ ((srow >> 1) & 3)) << 3);   // swizzled global k-chunk
    const unsigned short* Ap0 = A + (size_t)(bm * 128 + srow) * K + schunk;
    const unsigned short* Ap1 = A + (size_t)(bm * 128 + srow + 16) * K + schunk;
    const unsigned short* Bp0 = BT + (size_t)(bn * 128 + srow) * K + schunk;
    const unsigned short* Bp1 = BT + (size_t)(bn * 128 + srow + 16) * K + schunk;
    int d0 = (w * 32) * 32, d1 = (w * 32 + 16) * 32;

    int gx = ((g ^ ((lo >> 1) & 3)) << 3);

#define STAGE(buf, kb)                    \
    do {                                  \
        gl16(Ap0 + (kb), As[buf] + d0);   \
        gl16(Ap1 + (kb), As[buf] + d1);   \
        gl16(Bp0 + (kb), Bs[buf] + d0);   \
        gl16(Bp1 + (kb), Bs[buf] + d1);   \
    } while (0)

#define WAIT4() asm volatile("s_waitcnt vmcnt(4)" ::: "memory")
#define WAIT0() asm volatile("s_waitcnt vmcnt(0)" ::: "memory")

#define COMPUTE(buf)                                                                     \
    do {                                                                                 \
        bf16x8 af[4], bfv[4];                                                            \
        _Pragma("unroll")                                                                \
        for (int m = 0; m < 4; ++m)                                                      \
            af[m] = *(const bf16x8*)(As[buf] + (wm * 64 + m * 16 + lo) * 32 + gx);       \
        _Pragma("unroll")                                                                \
        for (int n = 0; n < 4; ++n)                                                      \
            bfv[n] = *(const bf16x8*)(Bs[buf] + (wn * 64 + n * 16 + lo) * 32 + gx);      \
        __builtin_amdgcn_s_setprio(1);                                                   \
        _Pragma("unroll")                                                                \
        for (int m = 0; m < 4; ++m)                                                      \
            _Pragma("unroll")                                                            \
            for (int n = 0; n < 4; ++n)                                                  \
                acc[m][n] = __builtin_amdgcn_mfma_f32_16x16x32_bf16(af[m], bfv[n],       \
                                                                    acc[m][n], 0, 0, 0); \
        __builtin_amdgcn_s_setprio(0);                                                   \
    } while (0)

    // prologue: 2 tiles in flight (8 outstanding vm ops per wave)
    STAGE(0, 0);
    STAGE(1, 32);

    int nt = K >> 5;   // 12 or 48 -> divisible by 3
    for (int tt = 0; tt < nt; tt += 3) {
        if (tt + 1 < nt) WAIT4(); else WAIT0();
        __builtin_amdgcn_s_barrier();
        if (tt + 2 < nt) STAGE(2, (tt + 2) * 32);
        COMPUTE(0);
        if (tt + 2 < nt) WAIT4(); else WAIT0();
        __builtin_amdgcn_s_barrier();
        if (tt + 3 < nt) STAGE(0, (tt + 3) * 32);
        COMPUTE(1);
        if (tt + 3 < nt) WAIT4(); else WAIT0();
        __builtin_amdgcn_s_barrier();
        if (tt + 4 < nt) STAGE(1, (tt + 4) * 32);
        COMPUTE(2);
    }
#undef STAGE
#undef WAIT4
#undef WAIT0
#undef COMPUTE

    int r0 = bm * 128 + wm * 64 + g * 4;
    int c0 = bn * 128 + wn * 64 + lo;
    // MODE 1 hoist: r>>6 == bm*2+wm (thread-constant since m*16+g*4+j < 64)
    int wgc = bm * 2 + wm;
    int bC = wgc / 49, winC = wgc % 49;
    int whC = winC / 7, wwC = winC % 7;
    int lC = (whC << 3) * 56 + (wwC << 3);
    size_t rowbaseC = (size_t)bC * 3136;
#pragma unroll
    for (int m = 0; m < 4; ++m)
#pragma unroll
        for (int n = 0; n < 4; ++n)
#pragma unroll
            for (int j = 0; j < 4; ++j) {
                int r = r0 + m * 16 + j;
                int c = c0 + n * 16;
                float v = acc[m][n][j] + bias[c];
                if (MODE == 0) {
                    ((unsigned short*)outp)[(size_t)r * N + c] = f2b(v);
                } else if (MODE == 1) {
                    int nn = m * 16 + (g << 2) + j;          // r & 63
                    int l = lC + (nn >> 3) * 56 + (nn & 7);
                    size_t idx = (rowbaseC + l) * 384 + c;
                    ((float*)outp)[idx] = ((const float*)aux0)[idx] + v;
                } else if (MODE == 2) {
                    ((unsigned short*)outp)[(size_t)r * N + c] = f2b(gelu_f(v));
                } else {
                    float res = ((const float*)aux0)[(size_t)r * 384 + c];
                    ((float*)outp)[(size_t)r * N + c] = v + res;
                }
            }
}

// ---------------- MFMA windowed attention: one wave per (window, head) ----------------
__global__ __launch_bounds__(64, 2) void win_attn_mfma(const unsigned short* __restrict__ qkv,
                                                       const unsigned short* __restrict__ gkb,
                                                       const unsigned short* __restrict__ gvb,
                                                       const float* __restrict__ rpb_mat,
                                                       unsigned short* __restrict__ ow) {
    int blk = blockIdx.x;
    int wg = blk / 12, h = blk % 12;
    int b = wg / 49, win = wg % 49;
    int wh = win / 7, ww = win % 7;
    int lane = threadIdx.x;
    int lo = lane & 15, g = lane >> 4;

    __shared__ __align__(16) unsigned short VT[32 * 136];
    __shared__ __align__(16) unsigned short PL[64 * 40];

    size_t qkvbase = (size_t)b * 3136 * 1152;
    int lbase = ((wh << 3)) * 56 + (ww << 3);

    {
        int n = lane;
        int l = lbase + (n >> 3) * 56 + (n & 7);
        const unsigned short* vp = qkv + qkvbase + (size_t)l * 1152 + 768 + h * 32;
        u16x8 v0 = *(const u16x8*)(vp);
        u16x8 v1 = *(const u16x8*)(vp + 8);
        u16x8 v2 = *(const u16x8*)(vp + 16);
        u16x8 v3 = *(const u16x8*)(vp + 24);
#pragma unroll
        for (int j = 0; j < 8; ++j) {
            VT[(0 + j) * 136 + n]  = v0[j];
            VT[(8 + j) * 136 + n]  = v1[j];
            VT[(16 + j) * 136 + n] = v2[j];
            VT[(24 + j) * 136 + n] = v3[j];
        }
        const unsigned short* gp = gvb + ((size_t)b * 64 + n) * 384 + h * 32;
        v0 = *(const u16x8*)(gp);
        v1 = *(const u16x8*)(gp + 8);
        v2 = *(const u16x8*)(gp + 16);
        v3 = *(const u16x8*)(gp + 24);
#pragma unroll
        for (int j = 0; j < 8; ++j) {
            VT[(0 + j) * 136 + 64 + n]  = v0[j];
            VT[(8 + j) * 136 + 64 + n]  = v1[j];
            VT[(16 + j) * 136 + 64 + n] = v2[j];
            VT[(24 + j) * 136 + 64 + n] = v3[j];
        }
    }

    bf16x8 qf[4];
#pragma unroll
    for (int qt = 0; qt < 4; ++qt) {
        int n = qt * 16 + lo;
        int l = lbase + (n >> 3) * 56 + (n & 7);
        qf[qt] = *(const bf16x8*)(qkv + qkvbase + (size_t)l * 1152 + h * 32 + g * 8);
    }

    f32x4 S[4][8];
#pragma unroll
    for (int qt = 0; qt < 4; ++qt)
#pragma unroll
        for (int t = 0; t < 8; ++t) S[qt][t] = f32x4{0.f, 0.f, 0.f, 0.f};

#pragma unroll
    for (int t = 0; t < 8; ++t) {
        bf16x8 kf;
        if (t < 4) {
            int key = t * 16 + lo;
            int l = lbase + (key >> 3) * 56 + (key & 7);
            kf = *(const bf16x8*)(qkv + qkvbase + (size_t)l * 1152 + 384 + h * 32 + g * 8);
        } else {
            int gkey = (t - 4) * 16 + lo;
            kf = *(const bf16x8*)(gkb + ((size_t)b * 64 + gkey) * 384 + h * 32 + g * 8);
        }
#pragma unroll
        for (int qt = 0; qt < 4; ++qt)
            S[qt][t] = __builtin_amdgcn_mfma_f32_16x16x32_bf16(qf[qt], kf, S[qt][t], 0, 0, 0);
    }

    const float* rb_h = rpb_mat + (size_t)h * 4096;
    float mx[4][4];
#pragma unroll
    for (int qt = 0; qt < 4; ++qt)
#pragma unroll
        for (int j = 0; j < 4; ++j) mx[qt][j] = -1e30f;

#pragma unroll
    for (int qt = 0; qt < 4; ++qt) {
#pragma unroll
        for (int t = 0; t < 8; ++t) {
#pragma unroll
            for (int j = 0; j < 4; ++j) {
                float v = S[qt][t][j] * SCALE_ATT;
                if (t < 4) v += rb_h[(qt * 16 + g * 4 + j) * 64 + t * 16 + lo];
                S[qt][t][j] = v;
                mx[qt][j] = fmaxf(mx[qt][j], v);
            }
        }
    }
#pragma unroll
    for (int qt = 0; qt < 4; ++qt)
#pragma unroll
        for (int j = 0; j < 4; ++j) {
#pragma unroll
            for (int m = 1; m <= 8; m <<= 1)
                mx[qt][j] = fmaxf(mx[qt][j], __shfl_xor(mx[qt][j], m));
        }

    float sm[4][4];
#pragma unroll
    for (int qt = 0; qt < 4; ++qt)
#pragma unroll
        for (int j = 0; j < 4; ++j) sm[qt][j] = 0.f;
#pragma unroll
    for (int qt = 0; qt < 4; ++qt)
#pragma unroll
        for (int t = 0; t < 8; ++t)
#pragma unroll
            for (int j = 0; j < 4; ++j) {
                float p = __expf(S[qt][t][j] - mx[qt][j]);
                S[qt][t][j] = p;
                sm[qt][j] += p;
            }
#pragma unroll
    for (int qt = 0; qt < 4; ++qt)
#pragma unroll
        for (int j = 0; j < 4; ++j) {
#pragma unroll
            for (int m = 1; m <= 8; m <<= 1)
                sm[qt][j] += __shfl_xor(sm[qt][j], m);
        }
    float inv[4][4];
#pragma unroll
    for (int qt = 0; qt < 4; ++qt)
#pragma unroll
        for (int j = 0; j < 4; ++j) inv[qt][j] = 1.f / sm[qt][j];

    f32x4 O[4][2];
#pragma unroll
    for (int qt = 0; qt < 4; ++qt)
#pragma unroll
        for (int dt = 0; dt < 2; ++dt) O[qt][dt] = f32x4{0.f, 0.f, 0.f, 0.f};

#pragma unroll
    for (int c = 0; c < 4; ++c) {
        __syncthreads();
#pragma unroll
        for (int qt = 0; qt < 4; ++qt) {
            int qb = qt * 16 + g * 4;
#pragma unroll
            for (int half = 0; half < 2; ++half) {
                int t = 2 * c + half;
#pragma unroll
                for (int j = 0; j < 4; ++j)
                    PL[(qb + j) * 40 + half * 16 + lo] = f2b_fast(S[qt][t][j]);
            }
        }
        __syncthreads();
#pragma unroll
        for (int qt = 0; qt < 4; ++qt) {
            bf16x8 pa = *(const bf16x8*)(PL + (qt * 16 + lo) * 40 + g * 8);
#pragma unroll
            for (int dt = 0; dt < 2; ++dt) {
                bf16x8 vb = *(const bf16x8*)(VT + (dt * 16 + lo) * 136 + c * 32 + g * 8);
                O[qt][dt] = __builtin_amdgcn_mfma_f32_16x16x32_bf16(pa, vb, O[qt][dt], 0, 0, 0);
            }
        }
    }

#pragma unroll
    for (int qt = 0; qt < 4; ++qt)
#pragma unroll
        for (int dt = 0; dt < 2; ++dt)
#pragma unroll
            for (int j = 0; j < 4; ++j) {
                int q = qt * 16 + g * 4 + j;
                int d = dt * 16 + lo;
                ow[((size_t)wg * 64 + q) * 384 + h * 32 + d] = f2b_fast(O[qt][dt][j] * inv[qt][j]);
            }
}

// ---------------- workspace layout (bytes) ----------------
static const size_t OFF_XN   = 0;             // ushort 50176*384   (later: ln2out)
static const size_t OFF_QKV  = 38535168;      // ushort 50176*1152  (later: h)
static const size_t OFF_OW   = 154140672;     // ushort 50176*384
static const size_t OFF_X2   = 192675840;     // float  50176*384
static const size_t OFF_PL   = 269746176;     // float  784*384 (pooled; later: rpb_mat)
static const size_t OFF_KEY  = 270950400;     // float  784*384
static const size_t OFF_VAL  = 272154624;     // float  784*384
static const size_t OFF_O    = 273358848;     // float  1024*384
static const size_t OFF_GK   = 274931712;     // ushort 1024*384
static const size_t OFF_GV   = 276504576;     // ushort 1024*384
static const size_t OFF_QKVW = 278077440;     // ushort 1152*384 (W^T [N][K])
static const size_t OFF_PRJW = 278962176;     // ushort 384*384
static const size_t OFF_FC1W = 279257088;     // ushort 1536*384
static const size_t OFF_FC2W = 280436736;     // ushort 384*1536   (end: 281,616,384)

extern "C" void kernel_launch(void* const* d_in, const int* in_sizes, int n_in,
                              void* d_out, int out_size, void* d_ws, size_t ws_size,
                              hipStream_t stream) {
    const float* x      = (const float*)d_in[0];
    const float* qtok   = (const float*)d_in[1];
    const float* kprojw = (const float*)d_in[2];
    const float* kprojb = (const float*)d_in[3];
    const float* kbng   = (const float*)d_in[4];
    const float* kbnb   = (const float*)d_in[5];
    const float* vprojw = (const float*)d_in[6];
    const float* vprojb = (const float*)d_in[7];
    const float* vbng   = (const float*)d_in[8];
    const float* vbnb   = (const float*)d_in[9];
    const float* ckw    = (const float*)d_in[10];
    const float* ckb    = (const float*)d_in[11];
    const float* cvw    = (const float*)d_in[12];
    const float* cvb    = (const float*)d_in[13];
    const float* qkvw   = (const float*)d_in[14];
    const float* qkvb   = (const float*)d_in[15];
    const float* projw  = (const float*)d_in[16];
    const float* projb  = (const float*)d_in[17];
    const float* rpbt   = (const float*)d_in[18];
    const float* n1g    = (const float*)d_in[19];
    const float* n1b    = (const float*)d_in[20];
    const float* n2g    = (const float*)d_in[21];
    const float* n2b    = (const float*)d_in[22];
    const float* fc1w   = (const float*)d_in[23];
    const float* fc1b   = (const float*)d_in[24];
    const float* fc2w   = (const float*)d_in[25];
    const float* fc2b   = (const float*)d_in[26];

    char* wsb = (char*)d_ws;
    unsigned short* xn     = (unsigned short*)(wsb + OFF_XN);
    unsigned short* qkvbf  = (unsigned short*)(wsb + OFF_QKV);
    unsigned short* owbf   = (unsigned short*)(wsb + OFF_OW);
    float* x2      = (float*)(wsb + OFF_X2);
    float* pooled  = (float*)(wsb + OFF_PL);
    float* rpb_mat = (float*)(wsb + OFF_PL);
    float* keyg    = (float*)(wsb + OFF_KEY);
    float* valg    = (float*)(wsb + OFF_VAL);
    float* obuf    = (float*)(wsb + OFF_O);
    unsigned short* gkb = (unsigned short*)(wsb + OFF_GK);
    unsigned short* gvb = (unsigned short*)(wsb + OFF_GV);
    unsigned short* qkvw_t = (unsigned short*)(wsb + OFF_QKVW);
    unsigned short* prjw_t = (unsigned short*)(wsb + OFF_PRJW);
    unsigned short* fc1w_t = (unsigned short*)(wsb + OFF_FC1W);
    unsigned short* fc2w_t = (unsigned short*)(wsb + OFF_FC2W);
    unsigned short* ln2out = (unsigned short*)(wsb + OFF_XN);     // reuse xn
    unsigned short* hbuf   = (unsigned short*)(wsb + OFF_QKV);    // reuse qkv(+ow)

    // 0. convert + transpose all 4 weights to bf16 [N][K] (one launch)
    cvt_all<<<6912, 256, 0, stream>>>(qkvw, projw, fc1w, fc2w, qkvw_t, prjw_t, fc1w_t, fc2w_t);
    // 1. LN1
    ln_kernel<<<50176, 64, 0, stream>>>(x, n1g, n1b, xn);
    // 2. pool + k/v proj
    pool_kernel<<<784, 384, 0, stream>>>(xn, pooled);
    kvproj_kernel<<<784, 128, 0, stream>>>(pooled, kprojw, kprojb, kbng, kbnb,
                                           vprojw, vprojb, vbng, vbnb, keyg, valg);
    // 2b. rpb dense expand
    rpb_expand_kernel<<<768, 64, 0, stream>>>(rpbt, rpb_mat);
    // 3. cross attention
    cross_attn_kernel<<<192, 64, 0, stream>>>(keyg, valg, qtok, obuf);
    // 4. gk/gv
    gkv_kernel<<<1024, 128, 0, stream>>>(obuf, qtok, ckw, ckb, cvw, cvb, gkb, gvb);
    // 5. qkv GEMM  [50176 x 1152 x 384]
    gemm128<0><<<dim3(9, 392), 256, 0, stream>>>(xn, qkvw_t, qkvb, 1152, 384, qkvbf, nullptr);
    // 6. windowed attention (MFMA)
    win_attn_mfma<<<9408, 64, 0, stream>>>(qkvbf, gkb, gvb, rpb_mat, owbf);
    // 7. proj GEMM + window reverse + residual -> x2 (fp32)
    gemm128<1><<<dim3(3, 392), 256, 0, stream>>>(owbf, prjw_t, projb, 384, 384, x2, x);
    // 8. LN2 -> bf16 scratch
    ln_kernel<<<50176, 64, 0, stream>>>(x2, n2g, n2b, ln2out);
    // 9. fc1 + GELU  [50176 x 1536 x 384]
    gemm128<2><<<dim3(12, 392), 256, 0, stream>>>(ln2out, fc1w_t, fc1b, 1536, 384, hbuf, nullptr);
    // 10. fc2 + residual  [50176 x 384 x 1536] -> fp32 d_out
    gemm128<3><<<dim3(3, 392), 256, 0, stream>>>(hbuf, fc2w_t, fc2b, 384, 1536, (float*)d_out, x2);
}

// Round 18
// 692.960 us; speedup vs baseline: 1.1720x; 1.0075x over previous
//
#include <hip/hip_runtime.h>
#include <math.h>

typedef __attribute__((ext_vector_type(8))) __bf16 bf16x8;
typedef __attribute__((ext_vector_type(4))) float f32x4;
typedef __attribute__((ext_vector_type(8))) unsigned short u16x8;

#define DI __device__ __forceinline__

DI float b2f(unsigned short u) { return __uint_as_float(((unsigned int)u) << 16); }
DI unsigned short f2b(float f) {
    unsigned int x = __float_as_uint(f);
    x += 0x7fffu + ((x >> 16) & 1u);   // round-to-nearest-even
    return (unsigned short)(x >> 16);
}
DI unsigned short f2b_fast(float f) {
    __bf16 h = (__bf16)f;
    return *(unsigned short*)&h;
}

// async global -> LDS, 16 B per lane (dest = wave-uniform base + lane*16)
DI void gl16(const unsigned short* g, unsigned short* l) {
    __builtin_amdgcn_global_load_lds(
        (const __attribute__((address_space(1))) void*)g,
        (__attribute__((address_space(3))) void*)l,
        16, 0, 0);
}

// tanh-GELU, algebraic: 0.5v(1+tanh(u)) == v * sigmoid(2u)
DI float gelu_f(float v) {
    float y = -1.5957691216f * v - 0.0713548163f * v * v * v;   // -2u
    return v * __builtin_amdgcn_rcpf(1.f + __expf(y));
}

// B=16, H=W=56, L=3136, C=384, NH=12, HD=32, WS=8, nW=49, N=64, NQ=64, MLP_H=1536
#define SCALE_ATT 0.17677669529663687f
#define BN_SCALE  0.9999950000374997f   // 1/sqrt(1+1e-5)

// ---------------- merged fp32 [K][N] -> bf16 [N][K] for all 4 weights ----------------
__global__ __launch_bounds__(256) void cvt_all(const float* __restrict__ s0, const float* __restrict__ s1,
                                               const float* __restrict__ s2, const float* __restrict__ s3,
                                               unsigned short* __restrict__ d0, unsigned short* __restrict__ d1,
                                               unsigned short* __restrict__ d2, unsigned short* __restrict__ d3) {
    int b = blockIdx.x;
    const float* in;
    unsigned short* out;
    int Kd, Nd, i0;
    if (b < 1728)      { in = s0; out = d0; Kd = 384;  Nd = 1152; i0 = b * 256; }
    else if (b < 2304) { in = s1; out = d1; Kd = 384;  Nd = 384;  i0 = (b - 1728) * 256; }
    else if (b < 4608) { in = s2; out = d2; Kd = 384;  Nd = 1536; i0 = (b - 2304) * 256; }
    else               { in = s3; out = d3; Kd = 1536; Nd = 384;  i0 = (b - 4608) * 256; }
    int i = i0 + threadIdx.x;
    if (i < Kd * Nd) {
        int k = i / Nd, n = i % Nd;
        out[(size_t)n * Kd + k] = f2b(in[i]);
    }
}

// ---------------- LayerNorm (row = 384), fp32 in -> bf16 out, vectorized ----------------
__global__ __launch_bounds__(64) void ln_kernel(const float* __restrict__ xin,
                                                const float* __restrict__ g,
                                                const float* __restrict__ bsh,
                                                unsigned short* __restrict__ out) {
    int row = blockIdx.x;
    int t = threadIdx.x;
    size_t base = (size_t)row * 384;
    float2 v[3];
    float s = 0.f, q = 0.f;
#pragma unroll
    for (int p = 0; p < 3; ++p) {
        v[p] = *(const float2*)(xin + base + p * 128 + t * 2);
        s += v[p].x + v[p].y;
        q += v[p].x * v[p].x + v[p].y * v[p].y;
    }
#pragma unroll
    for (int off = 32; off > 0; off >>= 1) {
        s += __shfl_xor(s, off);
        q += __shfl_xor(q, off);
    }
    float mu = s * (1.f / 384.f);
    float rstd = rsqrtf(q * (1.f / 384.f) - mu * mu + 1e-5f);
#pragma unroll
    for (int p = 0; p < 3; ++p) {
        int c = p * 128 + t * 2;
        unsigned int lo16 = f2b((v[p].x - mu) * rstd * g[c] + bsh[c]);
        unsigned int hi16 = f2b((v[p].y - mu) * rstd * g[c + 1] + bsh[c + 1]);
        ((unsigned int*)(out + base + p * 128))[t] = lo16 | (hi16 << 16);
    }
}

// ---------------- 8x8 average pool ----------------
__global__ __launch_bounds__(384) void pool_kernel(const unsigned short* __restrict__ xn,
                                                   float* __restrict__ pooled) {
    int blk = blockIdx.x;
    int b = blk / 49, pp = blk % 49;
    int ph = pp / 7, pw = pp % 7;
    int c = threadIdx.x;
    float s = 0.f;
    for (int i = 0; i < 8; ++i) {
        size_t rb = ((size_t)b * 3136 + (size_t)(ph * 8 + i) * 56 + pw * 8) * 384;
        for (int j = 0; j < 8; ++j) s += b2f(xn[rb + (size_t)j * 384 + c]);
    }
    pooled[(size_t)blk * 384 + c] = s * (1.f / 64.f);
}

// ---------------- key/value conv1x1 + BN ----------------
__global__ __launch_bounds__(128) void kvproj_kernel(
    const float* __restrict__ pooled,
    const float* __restrict__ kw, const float* __restrict__ kb,
    const float* __restrict__ kg, const float* __restrict__ kbb,
    const float* __restrict__ vw, const float* __restrict__ vb,
    const float* __restrict__ vg, const float* __restrict__ vbb,
    float* __restrict__ keyo, float* __restrict__ valo) {
    __shared__ float row[384];
    int r = blockIdx.x;
    int t = threadIdx.x;
    for (int c = t; c < 384; c += 128) row[c] = pooled[(size_t)r * 384 + c];
    __syncthreads();
#pragma unroll
    for (int p = 0; p < 3; ++p) {
        int c = t + 128 * p;
        float aK = 0.f, aV = 0.f;
        for (int k = 0; k < 384; ++k) {
            float rv = row[k];
            aK += rv * kw[(size_t)k * 384 + c];
            aV += rv * vw[(size_t)k * 384 + c];
        }
        keyo[(size_t)r * 384 + c] = (aK + kb[c]) * BN_SCALE * kg[c] + kbb[c];
        valo[(size_t)r * 384 + c] = (aV + vb[c]) * BN_SCALE * vg[c] + vbb[c];
    }
}

// ---------------- rel-pos bias expand ----------------
__global__ __launch_bounds__(64) void rpb_expand_kernel(const float* __restrict__ rpbt,
                                                        float* __restrict__ rpb_mat) {
    int h = blockIdx.x >> 6, q = blockIdx.x & 63;
    int k = threadIdx.x;
    int i1 = q >> 3, j1 = q & 7, i2 = k >> 3, j2 = k & 7;
    rpb_mat[((size_t)h * 64 + q) * 64 + k] = rpbt[(size_t)((i1 - i2 + 7) * 15 + (j1 - j2 + 7)) * 12 + h];
}

// ---------------- global cross attention ----------------
__global__ __launch_bounds__(64) void cross_attn_kernel(const float* __restrict__ keyg,
                                                        const float* __restrict__ valg,
                                                        const float* __restrict__ qtok,
                                                        float* __restrict__ o) {
    int b = blockIdx.x / 12, h = blockIdx.x % 12;
    __shared__ float kk[49][32];
    __shared__ float vv[49][32];
    int t = threadIdx.x;
    for (int idx = t; idx < 49 * 32; idx += 64) {
        int k = idx >> 5, d = idx & 31;
        size_t gidx = ((size_t)b * 49 + k) * 384 + h * 32 + d;
        kk[k][d] = keyg[gidx];
        vv[k][d] = valg[gidx];
    }
    __syncthreads();
    float q[32];
#pragma unroll
    for (int d = 0; d < 32; ++d) q[d] = qtok[(size_t)t * 384 + h * 32 + d] * SCALE_ATT;
    float lg[49];
    float mx = -1e30f;
#pragma unroll
    for (int k = 0; k < 49; ++k) {
        float s = 0.f;
#pragma unroll
        for (int d = 0; d < 32; ++d) s += q[d] * kk[k][d];
        lg[k] = s;
        mx = fmaxf(mx, s);
    }
    float sum = 0.f;
#pragma unroll
    for (int k = 0; k < 49; ++k) { float e = expf(lg[k] - mx); lg[k] = e; sum += e; }
    float inv = 1.f / sum;
    float od[32];
#pragma unroll
    for (int d = 0; d < 32; ++d) od[d] = 0.f;
#pragma unroll
    for (int k = 0; k < 49; ++k) {
        float wgt = lg[k];
#pragma unroll
        for (int d = 0; d < 32; ++d) od[d] += wgt * vv[k][d];
    }
#pragma unroll
    for (int d = 0; d < 32; ++d) o[((size_t)b * 64 + t) * 384 + h * 32 + d] = od[d] * inv;
}

// ---------------- gk/gv ----------------
__global__ __launch_bounds__(128) void gkv_kernel(
    const float* __restrict__ o, const float* __restrict__ qtok,
    const float* __restrict__ ckw, const float* __restrict__ ckb,
    const float* __restrict__ cvw, const float* __restrict__ cvb,
    unsigned short* __restrict__ gk, unsigned short* __restrict__ gv) {
    __shared__ float row[384];
    int r = blockIdx.x;
    int n = r & 63;
    int t = threadIdx.x;
    for (int c = t; c < 384; c += 128)
        row[c] = o[(size_t)r * 384 + c] + qtok[(size_t)n * 384 + c];
    __syncthreads();
#pragma unroll
    for (int p = 0; p < 3; ++p) {
        int c = t + 128 * p;
        float aK = 0.f, aV = 0.f;
        for (int k = 0; k < 384; ++k) {
            float rv = row[k];
            aK += rv * ckw[(size_t)k * 384 + c];
            aV += rv * cvw[(size_t)k * 384 + c];
        }
        gk[(size_t)r * 384 + c] = f2b(aK + ckb[c]);
        gv[(size_t)r * 384 + c] = f2b(aV + cvb[c]);
    }
}

// ---------------- MFMA GEMM, 128x128 tile, 4 waves, 3-buffer counted-vmcnt + T2 swizzle ----------------
// Best measured structure (r14/r17, ~697us): BK=32, 3 LDS buffers (48KB), prologue stages 2 tiles,
// per tile {vmcnt(4); s_barrier; STAGE(t+2); ds_read + setprio(1) MFMA setprio(0)}.
// Chunk swizzle pc = c ^ ((row>>1)&3) on global source (rule #21), read-side XOR; 0 conflicts (r9).
template <int MODE>
__global__ __launch_bounds__(256, 3) void gemm128(const unsigned short* __restrict__ A,
                                                  const unsigned short* __restrict__ BT,
                                                  const float* __restrict__ bias,
                                                  int N, int K,
                                                  void* __restrict__ outp,
                                                  const void* __restrict__ aux0) {
    __shared__ __align__(16) unsigned short As[3][128 * 32];
    __shared__ __align__(16) unsigned short Bs[3][128 * 32];

    // XCD-aware bijective swizzle
    int nwg = gridDim.x * gridDim.y;
    int flat = blockIdx.y * gridDim.x + blockIdx.x;
    int flat2 = (flat & 7) * (nwg >> 3) + (flat >> 3);
    int bn = flat2 % gridDim.x, bm = flat2 / gridDim.x;

    int t = threadIdx.x;
    int w = t >> 6, lane = t & 63;
    int wm = w >> 1, wn = w & 1;
    int lo = lane & 15, g = lane >> 4;

    f32x4 acc[4][4];
#pragma unroll
    for (int i = 0; i < 4; ++i)
#pragma unroll
        for (int j = 0; j < 4; ++j) acc[i][j] = f32x4{0.f, 0.f, 0.f, 0.f};

    int srow = w * 32 + (lane >> 2);
    int schunk = (((lane & 3) ^ ((srow >> 1) & 3)) << 3);   // swizzled global k-chunk
    const unsigned short* Ap0 = A + (size_t)(bm * 128 + srow) * K + schunk;
    const unsigned short* Ap1 = A + (size_t)(bm * 128 + srow + 16) * K + schunk;
    const unsigned short* Bp0 = BT + (size_t)(bn * 128 + srow) * K + schunk;
    const unsigned short* Bp1 = BT + (size_t)(bn * 128 + srow + 16) * K + schunk;
    int d0 = (w * 32) * 32, d1 = (w * 32 + 16) * 32;

    int gx = ((g ^ ((lo >> 1) & 3)) << 3);

#define STAGE(buf, kb)                    \
    do {                                  \
        gl16(Ap0 + (kb), As[buf] + d0);   \
        gl16(Ap1 + (kb), As[buf] + d1);   \
        gl16(Bp0 + (kb), Bs[buf] + d0);   \
        gl16(Bp1 + (kb), Bs[buf] + d1);   \
    } while (0)

#define WAIT4() asm volatile("s_waitcnt vmcnt(4)" ::: "memory")
#define WAIT0() asm volatile("s_waitcnt vmcnt(0)" ::: "memory")

#define COMPUTE(buf)                                                                     \
    do {                                                                                 \
        bf16x8 af[4], bfv[4];                                                            \
        _Pragma("unroll")                                                                \
        for (int m = 0; m < 4; ++m)                                                      \
            af[m] = *(const bf16x8*)(As[buf] + (wm * 64 + m * 16 + lo) * 32 + gx);       \
        _Pragma("unroll")                                                                \
        for (int n = 0; n < 4; ++n)                                                      \
            bfv[n] = *(const bf16x8*)(Bs[buf] + (wn * 64 + n * 16 + lo) * 32 + gx);      \
        __builtin_amdgcn_s_setprio(1);                                                   \
        _Pragma("unroll")                                                                \
        for (int m = 0; m < 4; ++m)                                                      \
            _Pragma("unroll")                                                            \
            for (int n = 0; n < 4; ++n)                                                  \
                acc[m][n] = __builtin_amdgcn_mfma_f32_16x16x32_bf16(af[m], bfv[n],       \
                                                                    acc[m][n], 0, 0, 0); \
        __builtin_amdgcn_s_setprio(0);                                                   \
    } while (0)

    // prologue: 2 tiles in flight (8 outstanding vm ops per wave)
    STAGE(0, 0);
    STAGE(1, 32);

    int nt = K >> 5;   // 12 or 48 -> divisible by 3
    for (int tt = 0; tt < nt; tt += 3) {
        if (tt + 1 < nt) WAIT4(); else WAIT0();
        __builtin_amdgcn_s_barrier();
        if (tt + 2 < nt) STAGE(2, (tt + 2) * 32);
        COMPUTE(0);
        if (tt + 2 < nt) WAIT4(); else WAIT0();
        __builtin_amdgcn_s_barrier();
        if (tt + 3 < nt) STAGE(0, (tt + 3) * 32);
        COMPUTE(1);
        if (tt + 3 < nt) WAIT4(); else WAIT0();
        __builtin_amdgcn_s_barrier();
        if (tt + 4 < nt) STAGE(1, (tt + 4) * 32);
        COMPUTE(2);
    }
#undef STAGE
#undef WAIT4
#undef WAIT0
#undef COMPUTE

    int r0 = bm * 128 + wm * 64 + g * 4;
    int c0 = bn * 128 + wn * 64 + lo;
    // MODE 1 hoist: r>>6 == bm*2+wm (thread-constant since m*16+g*4+j < 64)
    int wgc = bm * 2 + wm;
    int bC = wgc / 49, winC = wgc % 49;
    int whC = winC / 7, wwC = winC % 7;
    int lC = (whC << 3) * 56 + (wwC << 3);
    size_t rowbaseC = (size_t)bC * 3136;
#pragma unroll
    for (int m = 0; m < 4; ++m)
#pragma unroll
        for (int n = 0; n < 4; ++n)
#pragma unroll
            for (int j = 0; j < 4; ++j) {
                int r = r0 + m * 16 + j;
                int c = c0 + n * 16;
                float v = acc[m][n][j] + bias[c];
                if (MODE == 0) {
                    ((unsigned short*)outp)[(size_t)r * N + c] = f2b(v);
                } else if (MODE == 1) {
                    int nn = m * 16 + (g << 2) + j;          // r & 63
                    int l = lC + (nn >> 3) * 56 + (nn & 7);
                    size_t idx = (rowbaseC + l) * 384 + c;
                    ((float*)outp)[idx] = ((const float*)aux0)[idx] + v;
                } else if (MODE == 2) {
                    ((unsigned short*)outp)[(size_t)r * N + c] = f2b(gelu_f(v));
                } else {
                    float res = ((const float*)aux0)[(size_t)r * 384 + c];
                    ((float*)outp)[(size_t)r * N + c] = v + res;
                }
            }
}

// ---------------- MFMA windowed attention: one wave per (window, head) ----------------
__global__ __launch_bounds__(64, 2) void win_attn_mfma(const unsigned short* __restrict__ qkv,
                                                       const unsigned short* __restrict__ gkb,
                                                       const unsigned short* __restrict__ gvb,
                                                       const float* __restrict__ rpb_mat,
                                                       unsigned short* __restrict__ ow) {
    int blk = blockIdx.x;
    int wg = blk / 12, h = blk % 12;
    int b = wg / 49, win = wg % 49;
    int wh = win / 7, ww = win % 7;
    int lane = threadIdx.x;
    int lo = lane & 15, g = lane >> 4;

    __shared__ __align__(16) unsigned short VT[32 * 136];
    __shared__ __align__(16) unsigned short PL[64 * 40];

    size_t qkvbase = (size_t)b * 3136 * 1152;
    int lbase = ((wh << 3)) * 56 + (ww << 3);

    {
        int n = lane;
        int l = lbase + (n >> 3) * 56 + (n & 7);
        const unsigned short* vp = qkv + qkvbase + (size_t)l * 1152 + 768 + h * 32;
        u16x8 v0 = *(const u16x8*)(vp);
        u16x8 v1 = *(const u16x8*)(vp + 8);
        u16x8 v2 = *(const u16x8*)(vp + 16);
        u16x8 v3 = *(const u16x8*)(vp + 24);
#pragma unroll
        for (int j = 0; j < 8; ++j) {
            VT[(0 + j) * 136 + n]  = v0[j];
            VT[(8 + j) * 136 + n]  = v1[j];
            VT[(16 + j) * 136 + n] = v2[j];
            VT[(24 + j) * 136 + n] = v3[j];
        }
        const unsigned short* gp = gvb + ((size_t)b * 64 + n) * 384 + h * 32;
        v0 = *(const u16x8*)(gp);
        v1 = *(const u16x8*)(gp + 8);
        v2 = *(const u16x8*)(gp + 16);
        v3 = *(const u16x8*)(gp + 24);
#pragma unroll
        for (int j = 0; j < 8; ++j) {
            VT[(0 + j) * 136 + 64 + n]  = v0[j];
            VT[(8 + j) * 136 + 64 + n]  = v1[j];
            VT[(16 + j) * 136 + 64 + n] = v2[j];
            VT[(24 + j) * 136 + 64 + n] = v3[j];
        }
    }

    bf16x8 qf[4];
#pragma unroll
    for (int qt = 0; qt < 4; ++qt) {
        int n = qt * 16 + lo;
        int l = lbase + (n >> 3) * 56 + (n & 7);
        qf[qt] = *(const bf16x8*)(qkv + qkvbase + (size_t)l * 1152 + h * 32 + g * 8);
    }

    f32x4 S[4][8];
#pragma unroll
    for (int qt = 0; qt < 4; ++qt)
#pragma unroll
        for (int t = 0; t < 8; ++t) S[qt][t] = f32x4{0.f, 0.f, 0.f, 0.f};

#pragma unroll
    for (int t = 0; t < 8; ++t) {
        bf16x8 kf;
        if (t < 4) {
            int key = t * 16 + lo;
            int l = lbase + (key >> 3) * 56 + (key & 7);
            kf = *(const bf16x8*)(qkv + qkvbase + (size_t)l * 1152 + 384 + h * 32 + g * 8);
        } else {
            int gkey = (t - 4) * 16 + lo;
            kf = *(const bf16x8*)(gkb + ((size_t)b * 64 + gkey) * 384 + h * 32 + g * 8);
        }
#pragma unroll
        for (int qt = 0; qt < 4; ++qt)
            S[qt][t] = __builtin_amdgcn_mfma_f32_16x16x32_bf16(qf[qt], kf, S[qt][t], 0, 0, 0);
    }

    const float* rb_h = rpb_mat + (size_t)h * 4096;
    float mx[4][4];
#pragma unroll
    for (int qt = 0; qt < 4; ++qt)
#pragma unroll
        for (int j = 0; j < 4; ++j) mx[qt][j] = -1e30f;

#pragma unroll
    for (int qt = 0; qt < 4; ++qt) {
#pragma unroll
        for (int t = 0; t < 8; ++t) {
#pragma unroll
            for (int j = 0; j < 4; ++j) {
                float v = S[qt][t][j] * SCALE_ATT;
                if (t < 4) v += rb_h[(qt * 16 + g * 4 + j) * 64 + t * 16 + lo];
                S[qt][t][j] = v;
                mx[qt][j] = fmaxf(mx[qt][j], v);
            }
        }
    }
#pragma unroll
    for (int qt = 0; qt < 4; ++qt)
#pragma unroll
        for (int j = 0; j < 4; ++j) {
#pragma unroll
            for (int m = 1; m <= 8; m <<= 1)
                mx[qt][j] = fmaxf(mx[qt][j], __shfl_xor(mx[qt][j], m));
        }

    float sm[4][4];
#pragma unroll
    for (int qt = 0; qt < 4; ++qt)
#pragma unroll
        for (int j = 0; j < 4; ++j) sm[qt][j] = 0.f;
#pragma unroll
    for (int qt = 0; qt < 4; ++qt)
#pragma unroll
        for (int t = 0; t < 8; ++t)
#pragma unroll
            for (int j = 0; j < 4; ++j) {
                float p = __expf(S[qt][t][j] - mx[qt][j]);
                S[qt][t][j] = p;
                sm[qt][j] += p;
            }
#pragma unroll
    for (int qt = 0; qt < 4; ++qt)
#pragma unroll
        for (int j = 0; j < 4; ++j) {
#pragma unroll
            for (int m = 1; m <= 8; m <<= 1)
                sm[qt][j] += __shfl_xor(sm[qt][j], m);
        }
    float inv[4][4];
#pragma unroll
    for (int qt = 0; qt < 4; ++qt)
#pragma unroll
        for (int j = 0; j < 4; ++j) inv[qt][j] = 1.f / sm[qt][j];

    f32x4 O[4][2];
#pragma unroll
    for (int qt = 0; qt < 4; ++qt)
#pragma unroll
        for (int dt = 0; dt < 2; ++dt) O[qt][dt] = f32x4{0.f, 0.f, 0.f, 0.f};

#pragma unroll
    for (int c = 0; c < 4; ++c) {
        __syncthreads();
#pragma unroll
        for (int qt = 0; qt < 4; ++qt) {
            int qb = qt * 16 + g * 4;
#pragma unroll
            for (int half = 0; half < 2; ++half) {
                int t = 2 * c + half;
#pragma unroll
                for (int j = 0; j < 4; ++j)
                    PL[(qb + j) * 40 + half * 16 + lo] = f2b_fast(S[qt][t][j]);
            }
        }
        __syncthreads();
#pragma unroll
        for (int qt = 0; qt < 4; ++qt) {
            bf16x8 pa = *(const bf16x8*)(PL + (qt * 16 + lo) * 40 + g * 8);
#pragma unroll
            for (int dt = 0; dt < 2; ++dt) {
                bf16x8 vb = *(const bf16x8*)(VT + (dt * 16 + lo) * 136 + c * 32 + g * 8);
                O[qt][dt] = __builtin_amdgcn_mfma_f32_16x16x32_bf16(pa, vb, O[qt][dt], 0, 0, 0);
            }
        }
    }

#pragma unroll
    for (int qt = 0; qt < 4; ++qt)
#pragma unroll
        for (int dt = 0; dt < 2; ++dt)
#pragma unroll
            for (int j = 0; j < 4; ++j) {
                int q = qt * 16 + g * 4 + j;
                int d = dt * 16 + lo;
                ow[((size_t)wg * 64 + q) * 384 + h * 32 + d] = f2b_fast(O[qt][dt][j] * inv[qt][j]);
            }
}

// ---------------- workspace layout (bytes) ----------------
static const size_t OFF_XN   = 0;             // ushort 50176*384   (later: ln2out)
static const size_t OFF_QKV  = 38535168;      // ushort 50176*1152  (later: h)
static const size_t OFF_OW   = 154140672;     // ushort 50176*384
static const size_t OFF_X2   = 192675840;     // float  50176*384
static const size_t OFF_PL   = 269746176;     // float  784*384 (pooled; later: rpb_mat)
static const size_t OFF_KEY  = 270950400;     // float  784*384
static const size_t OFF_VAL  = 272154624;     // float  784*384
static const size_t OFF_O    = 273358848;     // float  1024*384
static const size_t OFF_GK   = 274931712;     // ushort 1024*384
static const size_t OFF_GV   = 276504576;     // ushort 1024*384
static const size_t OFF_QKVW = 278077440;     // ushort 1152*384 (W^T [N][K])
static const size_t OFF_PRJW = 278962176;     // ushort 384*384
static const size_t OFF_FC1W = 279257088;     // ushort 1536*384
static const size_t OFF_FC2W = 280436736;     // ushort 384*1536   (end: 281,616,384)

extern "C" void kernel_launch(void* const* d_in, const int* in_sizes, int n_in,
                              void* d_out, int out_size, void* d_ws, size_t ws_size,
                              hipStream_t stream) {
    const float* x      = (const float*)d_in[0];
    const float* qtok   = (const float*)d_in[1];
    const float* kprojw = (const float*)d_in[2];
    const float* kprojb = (const float*)d_in[3];
    const float* kbng   = (const float*)d_in[4];
    const float* kbnb   = (const float*)d_in[5];
    const float* vprojw = (const float*)d_in[6];
    const float* vprojb = (const float*)d_in[7];
    const float* vbng   = (const float*)d_in[8];
    const float* vbnb   = (const float*)d_in[9];
    const float* ckw    = (const float*)d_in[10];
    const float* ckb    = (const float*)d_in[11];
    const float* cvw    = (const float*)d_in[12];
    const float* cvb    = (const float*)d_in[13];
    const float* qkvw   = (const float*)d_in[14];
    const float* qkvb   = (const float*)d_in[15];
    const float* projw  = (const float*)d_in[16];
    const float* projb  = (const float*)d_in[17];
    const float* rpbt   = (const float*)d_in[18];
    const float* n1g    = (const float*)d_in[19];
    const float* n1b    = (const float*)d_in[20];
    const float* n2g    = (const float*)d_in[21];
    const float* n2b    = (const float*)d_in[22];
    const float* fc1w   = (const float*)d_in[23];
    const float* fc1b   = (const float*)d_in[24];
    const float* fc2w   = (const float*)d_in[25];
    const float* fc2b   = (const float*)d_in[26];

    char* wsb = (char*)d_ws;
    unsigned short* xn     = (unsigned short*)(wsb + OFF_XN);
    unsigned short* qkvbf  = (unsigned short*)(wsb + OFF_QKV);
    unsigned short* owbf   = (unsigned short*)(wsb + OFF_OW);
    float* x2      = (float*)(wsb + OFF_X2);
    float* pooled  = (float*)(wsb + OFF_PL);
    float* rpb_mat = (float*)(wsb + OFF_PL);
    float* keyg    = (float*)(wsb + OFF_KEY);
    float* valg    = (float*)(wsb + OFF_VAL);
    float* obuf    = (float*)(wsb + OFF_O);
    unsigned short* gkb = (unsigned short*)(wsb + OFF_GK);
    unsigned short* gvb = (unsigned short*)(wsb + OFF_GV);
    unsigned short* qkvw_t = (unsigned short*)(wsb + OFF_QKVW);
    unsigned short* prjw_t = (unsigned short*)(wsb + OFF_PRJW);
    unsigned short* fc1w_t = (unsigned short*)(wsb + OFF_FC1W);
    unsigned short* fc2w_t = (unsigned short*)(wsb + OFF_FC2W);
    unsigned short* ln2out = (unsigned short*)(wsb + OFF_XN);     // reuse xn
    unsigned short* hbuf   = (unsigned short*)(wsb + OFF_QKV);    // reuse qkv(+ow)

    // 0. convert + transpose all 4 weights to bf16 [N][K] (one launch)
    cvt_all<<<6912, 256, 0, stream>>>(qkvw, projw, fc1w, fc2w, qkvw_t, prjw_t, fc1w_t, fc2w_t);
    // 1. LN1
    ln_kernel<<<50176, 64, 0, stream>>>(x, n1g, n1b, xn);
    // 2. pool + k/v proj
    pool_kernel<<<784, 384, 0, stream>>>(xn, pooled);
    kvproj_kernel<<<784, 128, 0, stream>>>(pooled, kprojw, kprojb, kbng, kbnb,
                                           vprojw, vprojb, vbng, vbnb, keyg, valg);
    // 2b. rpb dense expand
    rpb_expand_kernel<<<768, 64, 0, stream>>>(rpbt, rpb_mat);
    // 3. cross attention
    cross_attn_kernel<<<192, 64, 0, stream>>>(keyg, valg, qtok, obuf);
    // 4. gk/gv
    gkv_kernel<<<1024, 128, 0, stream>>>(obuf, qtok, ckw, ckb, cvw, cvb, gkb, gvb);
    // 5. qkv GEMM  [50176 x 1152 x 384]
    gemm128<0><<<dim3(9, 392), 256, 0, stream>>>(xn, qkvw_t, qkvb, 1152, 384, qkvbf, nullptr);
    // 6. windowed attention (MFMA)
    win_attn_mfma<<<9408, 64, 0, stream>>>(qkvbf, gkb, gvb, rpb_mat, owbf);
    // 7. proj GEMM + window reverse + residual -> x2 (fp32)
    gemm128<1><<<dim3(3, 392), 256, 0, stream>>>(owbf, prjw_t, projb, 384, 384, x2, x);
    // 8. LN2 -> bf16 scratch
    ln_kernel<<<50176, 64, 0, stream>>>(x2, n2g, n2b, ln2out);
    // 9. fc1 + GELU  [50176 x 1536 x 384]
    gemm128<2><<<dim3(12, 392), 256, 0, stream>>>(ln2out, fc1w_t, fc1b, 1536, 384, hbuf, nullptr);
    // 10. fc2 + residual  [50176 x 384 x 1536] -> fp32 d_out
    gemm128<3><<<dim3(3, 392), 256, 0, stream>>>(hbuf, fc2w_t, fc2b, 384, 1536, (float*)d_out, x2);
}